// Round 6
// baseline (295.295 us; speedup 1.0000x reference)
//
#include <hip/hip_runtime.h>

#define MODE_QKV 0
#define MODE_S   1
#define MODE_PV  2

typedef __attribute__((ext_vector_type(8))) short short8;
typedef __attribute__((ext_vector_type(4))) float floatx4;

typedef const unsigned __attribute__((address_space(1)))* gp_t;
typedef unsigned __attribute__((address_space(3)))* lp_t;

__device__ __forceinline__ void async16(const void* g, void* l) {
  // stages 16B/lane: LDS dest = wave-uniform base + lane*16
  __builtin_amdgcn_global_load_lds((gp_t)g, (lp_t)l, 16, 0, 0);
}

__device__ __forceinline__ unsigned short f2bf(float f) {
  union { float f; unsigned u; } x; x.f = f;
  unsigned r = x.u + 0x7fffu + ((x.u >> 16) & 1u);
  return (unsigned short)(r >> 16);
}
__device__ __forceinline__ float bf2f(unsigned short h) {
  union { unsigned u; float f; } x; x.u = ((unsigned)h) << 16;
  return x.f;
}

// ===========================================================================
// R5 (resubmit): 256x256 kernel, 2 phases/K-tile with FRAGMENT REGISTER
// DOUBLE-BUFFERING. R2-R4 post-mortem: per-CU MFMA floor = 512x4.85 = 2480
// cyc/tile, LDS frag service = 192KB = 1500-2300 cyc/tile; the old 4-phase
// lockstep SERIALIZED them (measured 5600 cyc/tile, 26% MfmaUtil). This
// version issues next phase's ds_reads before this phase's MFMA and retires
// them with COUNTED lgkmcnt(8), so LDS service overlaps the MFMA window.
//
// Per-phase ledger (per wave, steady state), tile j, bufc=lds[(j&1)<<16]:
//  P(j,0): L1 read bb(j) 8 (FIRST) + aY(j) 8   [tile j landed: vmcnt @P(j-1,1)]
//          L2 lgkmcnt(8)   -> retires aX(j)-old + bb(j); leaves aY in flight
//          L3 s_barrier    -> all waves' bufc.A0/bb readers retired
//          L4 stage Ah1(j+1)->bufn.A1, Ah0(j+2)->bufc.A0   [regions idle]
//          L6 MFMA mh=0 (32) over aX,bb   [aY reads serviced underneath]
//  P(j,1): L1 vmcnt(2)     -> retires ALL of tile j+1 (youngest half issued
//                             one full phase earlier -> latency hidden)
//          L1 read aX(j+1) 8 from bufn.A0
//          L2 lgkmcnt(8)   -> retires aY(j); leaves aX(j+1)
//          L3 s_barrier; L4 stage Bh0/Bh1(j+2)->bufc.B
//          L6 MFMA mh=1 (32) over aY,bb   [aX(j+1) serviced underneath]
// Outstanding vmem: 6 -> +4(P0 stages) = 10 -> vmcnt(2) -> +4(P1) = 6. Every
// staged region's readers retired before an earlier barrier (checked per
// region). Tail: j=NT-2 vmcnt(0); j=NT-1 no stages/reads, lgkm(0).
// Barriers: 2/tile (was 8). MFMA ks outer (no dependent back-to-back).
//
// XOR swizzle unchanged (bank conflicts 6.6M -> 196K measured): physical 16B
// chunk = logical ^ (row&7), applied on the global source addr (linear
// global_load_lds dest) and on ds_read.
// ===========================================================================

__device__ __forceinline__ void stage_half(const unsigned short* gp, long rowbase,
                                           int ldk, int kb, char* region,
                                           int wave, int lane) {
  const int rs = lane >> 3;                    // row within 8-row group
  const int kc = ((lane & 7) ^ rs) << 3;       // pre-swizzled k-chunk (elems)
  #pragma unroll
  for (int h = 0; h < 2; h++) {
    const int rr = (h * 8 + wave) * 8 + rs;    // row within 128-row half
    async16(gp + (rowbase + rr) * (long)ldk + kb + kc,
            region + (h * 8 + wave) * 1024);
  }
}

__device__ __forceinline__ short8 frag(const char* region, int hr, int ks, int quad) {
  // logical chunk = ks*4+quad; physical = chunk ^ (hr&7); 16B chunks, 128B rows
  return *(const short8*)(region + hr * 128 + ((((ks << 2) | quad) ^ (hr & 7)) << 4));
}

// One phase's MFMA cluster: quadrants (MH,0) and (MH,1), ks OUTER so
// consecutive MFMAs never chain on the same accumulator.
#define MFMA_PH(MH, AREG)                                                    \
  do {                                                                       \
    _Pragma("unroll")                                                        \
    for (int ks_ = 0; ks_ < 2; ks_++) {                                      \
      _Pragma("unroll")                                                      \
      for (int mi_ = 0; mi_ < 4; mi_++) {                                    \
        _Pragma("unroll")                                                    \
        for (int nh_ = 0; nh_ < 2; nh_++) {                                  \
          _Pragma("unroll")                                                  \
          for (int jj_ = 0; jj_ < 2; jj_++) {                                \
            acc[MH][mi_][nh_][jj_] = __builtin_amdgcn_mfma_f32_16x16x32_bf16(\
                AREG[mi_][ks_], bb[nh_][jj_][ks_], acc[MH][mi_][nh_][jj_],   \
                0, 0, 0);                                                    \
          }                                                                  \
        }                                                                    \
      }                                                                      \
    }                                                                        \
  } while (0)

template<int MODE>
__global__ __launch_bounds__(512, 1)
void gemm256(const unsigned short* __restrict__ A,
             const unsigned short* __restrict__ Bmat,
             const float* __restrict__ b0, const float* __restrict__ b1,
             const float* __restrict__ b2,
             unsigned short* __restrict__ O0, unsigned short* __restrict__ O1,
             unsigned short* __restrict__ O2, float* __restrict__ Of,
             float* __restrict__ lsum,
             int M, int N, int K, long aZ, long bZ, long cZ, float scale)
{
  __shared__ __attribute__((aligned(128))) char lds[131072];

  const int tid = threadIdx.x;
  const int wave = tid >> 6, lane = tid & 63;
  const int wm = wave >> 2, wn = wave & 3;
  const int quad = lane >> 4, l16 = lane & 15;

  // ---- XCD-aware 4x4-square swizzle (requires total blocks % 128 == 0) ----
  const int gx = gridDim.x, gy = gridDim.y;
  int z, bm, bn;
  {
    int f = (blockIdx.z * gy + blockIdx.y) * gx + blockIdx.x;
    int T = gx * gy * (int)gridDim.z;
    int nsq = T >> 7;
    int xcd = f & 7, i = f >> 3;
    int sq = xcd * nsq + (i >> 4);
    int w = i & 15;
    int spz = (gx >> 2) * (gy >> 2);
    z = sq / spz;
    int sqr = sq - z * spz;
    int sqm = sqr / (gx >> 2), sqn = sqr - sqm * (gx >> 2);
    bm = (sqm * 4 + (w >> 2)) * 256;
    bn = (sqn * 4 + (w & 3)) * 256;
  }

  const unsigned short* Ap = (MODE == MODE_QKV) ? A : (A + (long)z * aZ);
  const unsigned short* Bp = Bmat + (long)z * bZ;

  const int NT = K >> 6;

  // region offsets within a buffer: A0=0, A1=16384, B0=32768, B1=49152
  // prologue: t0{A0,B0,B1,A1} + t1{A0,B0,B1} = 14 loads; vmcnt(6) -> tile 0
  // fully landed, tile 1's {A0,B0,B1} (6 loads) in flight.
  stage_half(Ap, bm,       K, 0,  lds +     0, wave, lane);
  stage_half(Bp, bn,       K, 0,  lds + 32768, wave, lane);
  stage_half(Bp, bn + 128, K, 0,  lds + 49152, wave, lane);
  stage_half(Ap, bm + 128, K, 0,  lds + 16384, wave, lane);
  stage_half(Ap, bm,       K, 64, lds + 65536 +     0, wave, lane);
  stage_half(Bp, bn,       K, 64, lds + 65536 + 32768, wave, lane);
  stage_half(Bp, bn + 128, K, 64, lds + 65536 + 49152, wave, lane);
  asm volatile("s_waitcnt vmcnt(6)" ::: "memory");
  asm volatile("s_barrier" ::: "memory");

  floatx4 acc[2][4][2][2];   // [mh][mi][nh][jj]
  #pragma unroll
  for (int p = 0; p < 2; p++)
    #pragma unroll
    for (int q2 = 0; q2 < 4; q2++)
      #pragma unroll
      for (int r = 0; r < 2; r++)
        #pragma unroll
        for (int s = 0; s < 2; s++)
          acc[p][q2][r][s] = (floatx4){0.f, 0.f, 0.f, 0.f};

  short8 aX[4][2];     // A-frags for phase 0 (A0 half of current tile)
  short8 aY[4][2];     // A-frags for phase 1 (A1 half of current tile)
  short8 bb[2][2][2];  // B-frags for current tile [nh][jj][ks]

  // pre-loop: issue aX(0) (tile 0 landed)
  #pragma unroll
  for (int mi = 0; mi < 4; mi++)
    #pragma unroll
    for (int ks = 0; ks < 2; ks++)
      aX[mi][ks] = frag(lds, wm * 64 + mi * 16 + l16, ks, quad);

  for (int j = 0; j < NT; j++) {
    char* bufc = lds + ((j & 1) << 16);
    char* bufn = lds + (((j + 1) & 1) << 16);
    const int kn  = (j + 1) << 6;
    const int kn2 = (j + 2) << 6;

    // ======== phase 0 : MFMA mh=0 over aX, bb ========
    // L1: bb FIRST (retired at L2), then aY (stays in flight under MFMA)
    #pragma unroll
    for (int nh = 0; nh < 2; nh++)
      #pragma unroll
      for (int jj = 0; jj < 2; jj++)
        #pragma unroll
        for (int ks = 0; ks < 2; ks++)
          bb[nh][jj][ks] = frag(bufc + 32768 + nh * 16384,
                                wn * 32 + jj * 16 + l16, ks, quad);
    #pragma unroll
    for (int mi = 0; mi < 4; mi++)
      #pragma unroll
      for (int ks = 0; ks < 2; ks++)
        aY[mi][ks] = frag(bufc + 16384, wm * 64 + mi * 16 + l16, ks, quad);
    asm volatile("s_waitcnt lgkmcnt(8)" ::: "memory");   // retire aX-old + bb
    asm volatile("s_barrier" ::: "memory");
    if (j + 1 < NT)
      stage_half(Ap, bm + 128, K, kn,  bufn + 16384, wave, lane);  // Ah1(j+1)
    if (j + 2 < NT)
      stage_half(Ap, bm,       K, kn2, bufc,         wave, lane);  // Ah0(j+2)
    __builtin_amdgcn_s_setprio(1);
    MFMA_PH(0, aX);
    __builtin_amdgcn_s_setprio(0);

    // ======== phase 1 : MFMA mh=1 over aY, bb ========
    if (j + 2 < NT) {
      asm volatile("s_waitcnt vmcnt(2)" ::: "memory");   // tile j+1 all landed
    } else {
      asm volatile("s_waitcnt vmcnt(0)" ::: "memory");
    }
    if (j + 1 < NT) {
      #pragma unroll
      for (int mi = 0; mi < 4; mi++)
        #pragma unroll
        for (int ks = 0; ks < 2; ks++)
          aX[mi][ks] = frag(bufn, wm * 64 + mi * 16 + l16, ks, quad);
      asm volatile("s_waitcnt lgkmcnt(8)" ::: "memory"); // retire aY
    } else {
      asm volatile("s_waitcnt lgkmcnt(0)" ::: "memory");
    }
    asm volatile("s_barrier" ::: "memory");
    if (j + 2 < NT) {
      stage_half(Bp, bn,       K, kn2, bufc + 32768, wave, lane);  // Bh0(j+2)
      stage_half(Bp, bn + 128, K, kn2, bufc + 49152, wave, lane);  // Bh1(j+2)
    }
    __builtin_amdgcn_s_setprio(1);
    MFMA_PH(1, aY);
    __builtin_amdgcn_s_setprio(0);
  }
  // All reads retired before the final barrier; staging fully drained at
  // tile NT-2's vmcnt(0). Sync before reusing LDS for the epilogue.
  __syncthreads();

  if (MODE == MODE_PV) {
    // fp32 direct stores, normalized by the row's exp-sum (M = rows/batch)
    #pragma unroll
    for (int mh = 0; mh < 2; mh++)
      #pragma unroll
      for (int mi = 0; mi < 4; mi++) {
        const int row0 = bm + mh * 128 + wm * 64 + mi * 16 + quad * 4;
        float inv[4];
        #pragma unroll
        for (int r = 0; r < 4; r++)
          inv[r] = 1.0f / lsum[(long)z * M + row0 + r];
        #pragma unroll
        for (int nh = 0; nh < 2; nh++)
          #pragma unroll
          for (int jj = 0; jj < 2; jj++) {
            const int col = bn + nh * 128 + wn * 32 + jj * 16 + l16;
            #pragma unroll
            for (int r = 0; r < 4; r++)
              Of[(long)z * cZ + (long)(row0 + r) * N + col] =
                  acc[mh][mi][nh][jj][r] * inv[r];
          }
      }
    return;
  }

  const bool vtrans = (MODE == MODE_QKV) && (z == 2);
  float bi[2][2];
  if (MODE == MODE_QKV) {
    const float* bias = (z == 0) ? b0 : ((z == 1) ? b1 : b2);
    #pragma unroll
    for (int nh = 0; nh < 2; nh++)
      #pragma unroll
      for (int jj = 0; jj < 2; jj++)
        bi[nh][jj] = bias[bn + nh * 128 + wn * 32 + jj * 16 + l16];
  }

  unsigned short* epi = (unsigned short*)lds;
  // two passes of 128 rows (pass = mh). normal/S: epi[128][264]; vtrans
  // (v output [B][D][S]): epi[256][136] transposed.
  #pragma unroll
  for (int mh = 0; mh < 2; mh++) {
    #pragma unroll
    for (int mi = 0; mi < 4; mi++) {
      const int r0 = wm * 64 + mi * 16 + quad * 4;
      #pragma unroll
      for (int nh = 0; nh < 2; nh++)
        #pragma unroll
        for (int jj = 0; jj < 2; jj++) {
          const int col = nh * 128 + wn * 32 + jj * 16 + l16;
          if (MODE == MODE_S) {
            #pragma unroll
            for (int r = 0; r < 4; r++)
              epi[(r0 + r) * 264 + col] = f2bf(__expf(acc[mh][mi][nh][jj][r] * scale));
          } else if (!vtrans) {
            #pragma unroll
            for (int r = 0; r < 4; r++)
              epi[(r0 + r) * 264 + col] = f2bf(acc[mh][mi][nh][jj][r] + bi[nh][jj]);
          } else {
            #pragma unroll
            for (int r = 0; r < 4; r += 2) {
              unsigned lo = f2bf(acc[mh][mi][nh][jj][r] + bi[nh][jj]);
              unsigned hi = f2bf(acc[mh][mi][nh][jj][r + 1] + bi[nh][jj]);
              *(unsigned*)&epi[col * 136 + r0 + r] = lo | (hi << 16);
            }
          }
        }
    }
    __syncthreads();

    if (!vtrans) {
      #pragma unroll
      for (int it = 0; it < 8; it++) {
        int flat = it * 4096 + tid * 8;
        int rr = flat >> 8, cc = flat & 255;
        short8 vline = *(const short8*)&epi[rr * 264 + cc];
        long grow = bm + mh * 128 + rr;
        if (MODE == MODE_S) {
          union { short8 v; unsigned short u[8]; } t; t.v = vline;
          float s8 = 0.f;
          #pragma unroll
          for (int jq = 0; jq < 8; jq++) s8 += bf2f(t.u[jq]);
          s8 += __shfl_xor(s8, 1);
          s8 += __shfl_xor(s8, 2);
          s8 += __shfl_xor(s8, 4);
          s8 += __shfl_xor(s8, 8);
          s8 += __shfl_xor(s8, 16);
          if ((lane & 31) == 0) atomicAdd(&lsum[(long)z * M + grow], s8);
          *(short8*)&O0[(long)z * cZ + grow * N + bn + cc] = vline;
        } else {
          unsigned short* O = (z == 0) ? O0 : O1;
          *(short8*)&O[grow * N + bn + cc] = vline;
        }
      }
    } else {
      int bb2 = bm >> 11, s0 = bm & 2047;  // S=2048; tiles don't straddle batch
      #pragma unroll
      for (int it = 0; it < 8; it++) {
        int flat = it * 4096 + tid * 8;
        int dd = flat >> 7, ss = flat & 127;
        short8 vline = *(const short8*)&epi[dd * 136 + ss];
        *(short8*)&O2[(long)bb2 * (1024L * 2048) + (long)(bn + dd) * 2048 + s0 + mh * 128 + ss] = vline;
      }
    }
    if (mh == 0) __syncthreads();
  }
}

// ===========================================================================
// Legacy 128x128 kernel (fallback path only)
// ===========================================================================

union SmemU {
  struct { unsigned short A[2][4096]; unsigned short B[2][4096]; } st;  // 32 KB
  unsigned short epi[128 * 136];                                        // 34816 B
};

template<int MODE>
__global__ __launch_bounds__(256, 4)
void gemm_nt(const unsigned short* __restrict__ A,
             const unsigned short* __restrict__ Bmat,
             const float* __restrict__ b0, const float* __restrict__ b1,
             const float* __restrict__ b2,
             unsigned short* __restrict__ O0, unsigned short* __restrict__ O1,
             unsigned short* __restrict__ O2,
             float* __restrict__ Of, float* __restrict__ lsum,
             int M, int N, int K, long aZ, long bZ, long cZ, float scale)
{
  __shared__ SmemU smem;

  const int tid = threadIdx.x;
  const int wave = tid >> 6, lane = tid & 63;
  const int wm = wave >> 1, wn = wave & 1;
  const int quad = lane >> 4, l16 = lane & 15;

  const int gx = gridDim.x, gy = gridDim.y;
  int z, bm, bn;
  {
    int f = (blockIdx.z * gy + blockIdx.y) * gx + blockIdx.x;
    int T = gx * gy * (int)gridDim.z;
    int nsq = T >> 7;
    int xcd = f & 7, i = f >> 3;
    int sq = xcd * nsq + (i >> 4);
    int w = i & 15;
    int spz = (gx >> 2) * (gy >> 2);
    z = sq / spz;
    int sqr = sq - z * spz;
    int sqm = sqr / (gx >> 2), sqn = sqr - sqm * (gx >> 2);
    bm = (sqm * 4 + (w >> 2)) * 128;
    bn = (sqn * 4 + (w & 3)) * 128;
  }

  const unsigned short* Ap = (MODE == MODE_QKV) ? A : (A + (long)z * aZ);
  const unsigned short* Bp = Bmat + (long)z * bZ;

  floatx4 acc[4][4];
  #pragma unroll
  for (int i = 0; i < 4; i++)
    #pragma unroll
    for (int j = 0; j < 4; j++)
      acc[i][j] = (floatx4){0.f, 0.f, 0.f, 0.f};

  char* asb = (char*)&smem.st.A[0][0] + wave * 1024;
  char* bsb = (char*)&smem.st.B[0][0] + wave * 1024;

  for (int k0 = 0; k0 < K; k0 += 64) {
    #pragma unroll
    for (int p = 0; p < 2; p++) {
      #pragma unroll
      for (int h = 0; h < 2; h++) {
        int flat = tid + h * 256;
        int r = flat >> 2, c = (flat & 3) << 3;
        async16(Ap + (long)(bm + r) * K + k0 + p * 32 + c,
                asb + p * 8192 + h * 4096);
        async16(Bp + (long)(bn + r) * K + k0 + p * 32 + c,
                bsb + p * 8192 + h * 4096);
      }
    }
    __syncthreads();

    #pragma unroll
    for (int ks = 0; ks < 2; ks++) {
      short8 afr[4], bfr[4];
      #pragma unroll
      for (int i = 0; i < 4; i++)
        afr[i] = *(const short8*)&smem.st.A[ks][(wm * 64 + i * 16 + l16) * 32 + quad * 8];
      #pragma unroll
      for (int i = 0; i < 4; i++)
        bfr[i] = *(const short8*)&smem.st.B[ks][(wn * 64 + i * 16 + l16) * 32 + quad * 8];
      #pragma unroll
      for (int mi = 0; mi < 4; mi++)
        #pragma unroll
        for (int ni = 0; ni < 4; ni++)
          acc[mi][ni] = __builtin_amdgcn_mfma_f32_16x16x32_bf16(
              afr[mi], bfr[ni], acc[mi][ni], 0, 0, 0);
    }
    __syncthreads();
  }

  if (MODE == MODE_PV) {
    #pragma unroll
    for (int mi = 0; mi < 4; mi++) {
      int row0 = bm + wm * 64 + mi * 16 + quad * 4;
      float inv[4];
      #pragma unroll
      for (int r = 0; r < 4; r++)
        inv[r] = 1.0f / lsum[(long)z * M + row0 + r];
      #pragma unroll
      for (int ni = 0; ni < 4; ni++) {
        int col = bn + wn * 64 + ni * 16 + l16;
        #pragma unroll
        for (int r = 0; r < 4; r++)
          Of[(long)z * cZ + (long)(row0 + r) * N + col] = acc[mi][ni][r] * inv[r];
      }
    }
    return;
  }

  const bool vtrans = (MODE == MODE_QKV) && (z == 2);
  float bi[4];
  if (MODE == MODE_QKV) {
    const float* bias = (z == 0) ? b0 : ((z == 1) ? b1 : b2);
    #pragma unroll
    for (int ni = 0; ni < 4; ni++) bi[ni] = bias[bn + wn * 64 + ni * 16 + l16];
  }

  #pragma unroll
  for (int ni = 0; ni < 4; ni++) {
    int col = wn * 64 + ni * 16 + l16;
    float bbias = (MODE == MODE_QKV) ? bi[ni] : 0.f;
    #pragma unroll
    for (int mi = 0; mi < 4; mi++) {
      int row0 = wm * 64 + mi * 16 + quad * 4;
      if (MODE == MODE_S) {
        #pragma unroll
        for (int r = 0; r < 4; r++)
          smem.epi[(row0 + r) * 136 + col] = f2bf(__expf(acc[mi][ni][r] * scale));
      } else if (!vtrans) {
        #pragma unroll
        for (int r = 0; r < 4; r++)
          smem.epi[(row0 + r) * 136 + col] = f2bf(acc[mi][ni][r] + bbias);
      } else {
        #pragma unroll
        for (int r = 0; r < 4; r += 2) {
          unsigned lo = f2bf(acc[mi][ni][r] + bbias);
          unsigned hi = f2bf(acc[mi][ni][r + 1] + bbias);
          *(unsigned*)&smem.epi[col * 136 + row0 + r] = lo | (hi << 16);
        }
      }
    }
  }
  __syncthreads();

  #pragma unroll
  for (int i = 0; i < 8; i++) {
    int flat = i * 2048 + tid * 8;
    int rr = flat >> 7, cc = flat & 127;
    short8 vline = *(const short8*)&smem.epi[rr * 136 + cc];
    if (MODE == MODE_S) {
      union { short8 v; unsigned short u[8]; } t; t.v = vline;
      float s8 = 0.f;
      #pragma unroll
      for (int j = 0; j < 8; j++) s8 += bf2f(t.u[j]);
      s8 += __shfl_xor(s8, 1);
      s8 += __shfl_xor(s8, 2);
      s8 += __shfl_xor(s8, 4);
      s8 += __shfl_xor(s8, 8);
      if ((lane & 15) == 0) atomicAdd(&lsum[(long)z * M + bm + rr], s8);
      *(short8*)&O0[(long)z * cZ + (long)(bm + rr) * N + bn + cc] = vline;
    } else if (!vtrans) {
      unsigned short* O = (z == 0) ? O0 : O1;
      *(short8*)&O[(long)(bm + rr) * N + bn + cc] = vline;
    } else {
      int bb = bm >> 11, s0 = bm & 2047;
      *(short8*)&O2[(long)bb * (1024L * 2048) + (long)(bn + rr) * 2048 + s0 + cc] = vline;
    }
  }
}

// Fused prep: [0,4096) x fp32->bf16; [4096,7168) W transpose->bf16;
// [7168,7200) zero the 8192-float lsum buffer.
__global__ __launch_bounds__(256)
void prep_kernel(const float* __restrict__ x, unsigned short* __restrict__ xb,
                 const float* __restrict__ W0, const float* __restrict__ W1,
                 const float* __restrict__ W2, unsigned short* __restrict__ Wt,
                 float* __restrict__ lsum) {
  int blk = blockIdx.x;
  if (blk < 4096) {
    long i = ((long)blk * 256 + threadIdx.x) * 8;
    float4 a = *(const float4*)(x + i);
    float4 b = *(const float4*)(x + i + 4);
    union { int4 v; unsigned short u[8]; } t;
    t.u[0] = f2bf(a.x); t.u[1] = f2bf(a.y); t.u[2] = f2bf(a.z); t.u[3] = f2bf(a.w);
    t.u[4] = f2bf(b.x); t.u[5] = f2bf(b.y); t.u[6] = f2bf(b.z); t.u[7] = f2bf(b.w);
    *(int4*)(xb + i) = t.v;
  } else if (blk < 7168) {
    __shared__ float tile[32][33];
    int tt = blk - 4096;
    int zz = tt >> 10, rem = tt & 1023;
    int kb = (rem >> 5) * 32, nb = (rem & 31) * 32;
    const float* W = (zz == 0) ? W0 : ((zz == 1) ? W1 : W2);
    unsigned short* O = Wt + (long)zz * 1024 * 1024;
    int t = threadIdx.x, tr = t >> 5, tc = t & 31;
    #pragma unroll
    for (int i = 0; i < 4; i++)
      tile[tr + i * 8][tc] = W[(long)(kb + tr + i * 8) * 1024 + nb + tc];
    __syncthreads();
    #pragma unroll
    for (int i = 0; i < 4; i++)
      O[(long)(nb + tr + i * 8) * 1024 + kb + tc] = f2bf(tile[tc][tr + i * 8]);
  } else {
    int i = (blk - 7168) * 256 + threadIdx.x;  // 32*256 = 8192 floats
    lsum[i] = 0.f;
  }
}

extern "C" void kernel_launch(void* const* d_in, const int* in_sizes, int n_in,
                              void* d_out, int out_size, void* d_ws, size_t ws_size,
                              hipStream_t stream) {
  const float* x  = (const float*)d_in[0];
  const float* Wq = (const float*)d_in[1];
  const float* bq = (const float*)d_in[2];
  const float* Wk = (const float*)d_in[3];
  const float* bk = (const float*)d_in[4];
  const float* Wv = (const float*)d_in[5];
  const float* bv = (const float*)d_in[6];
  float* out = (float*)d_out;

  const int B = 4, S = 2048, D = 1024;
  const int M = B * S;
  const float scale = 0.03125f;  // 1/sqrt(1024)

  // xb (16 MiB) + Wt (6 MiB) borrow d_out's first 22 MiB; dead before the
  // PV GEMM overwrites all of d_out.
  unsigned short* xb = (unsigned short*)d_out;
  unsigned short* Wt = xb + (size_t)M * D;
  unsigned short* q  = (unsigned short*)d_ws;
  unsigned short* k  = q + (size_t)M * D;
  unsigned short* vT = k + (size_t)M * D;
  unsigned short* P  = vT + (size_t)M * D;

  size_t need_full = ((size_t)3 * M * D + (size_t)B * S * S) * sizeof(unsigned short)
                   + (size_t)M * sizeof(float);
  const bool full = (ws_size >= need_full);
  float* lsum = full ? (float*)(P + (size_t)B * S * S)
                     : (float*)(P + (size_t)S * S);

  prep_kernel<<<7200, 256, 0, stream>>>(x, xb, Wq, Wk, Wv, Wt, lsum);

  gemm256<MODE_QKV><<<dim3(D / 256, M / 256, 3), 512, 0, stream>>>(
      xb, Wt, bq, bk, bv, q, k, vT, nullptr, nullptr,
      M, D, D, 0, (long)D * D, 0, 1.0f);

  if (full) {
    gemm256<MODE_S><<<dim3(S / 256, S / 256, B), 512, 0, stream>>>(
        q, k, nullptr, nullptr, nullptr, P, nullptr, nullptr, nullptr, lsum,
        S, S, D, (long)S * D, (long)S * D, (long)S * S, scale);
    gemm256<MODE_PV><<<dim3(D / 256, S / 256, B), 512, 0, stream>>>(
        P, vT, nullptr, nullptr, nullptr, nullptr, nullptr, nullptr, out, lsum,
        S, D, S, (long)S * S, (long)D * S, (long)S * D, 1.0f);
  } else {
    for (int b = 0; b < B; b++) {
      const unsigned short* qb = q + (size_t)b * S * D;
      const unsigned short* kb = k + (size_t)b * S * D;
      const unsigned short* vb = vT + (size_t)b * S * D;
      float* ob = out + (size_t)b * S * D;
      gemm_nt<MODE_S><<<dim3(S / 128, S / 128, 1), 256, 0, stream>>>(
          qb, kb, nullptr, nullptr, nullptr, P, nullptr, nullptr, nullptr,
          lsum + (size_t)b * S,
          S, S, D, 0, 0, 0, scale);
      gemm_nt<MODE_PV><<<dim3(D / 128, S / 128, 1), 256, 0, stream>>>(
          P, vb, nullptr, nullptr, nullptr, nullptr, nullptr, nullptr, ob,
          lsum + (size_t)b * S,
          S, D, S, 0, 0, 0, 1.0f);
    }
  }
}

// Round 7
// 238.894 us; speedup vs baseline: 1.2361x; 1.2361x over previous
//
#include <hip/hip_runtime.h>

#define MODE_QKV 0
#define MODE_S   1
#define MODE_PV  2

typedef __attribute__((ext_vector_type(8))) short short8;
typedef __attribute__((ext_vector_type(4))) float floatx4;

typedef const unsigned __attribute__((address_space(1)))* gp_t;
typedef unsigned __attribute__((address_space(3)))* lp_t;

__device__ __forceinline__ void async16(const void* g, void* l) {
  // stages 16B/lane: LDS dest = wave-uniform base + lane*16
  __builtin_amdgcn_global_load_lds((gp_t)g, (lp_t)l, 16, 0, 0);
}

__device__ __forceinline__ unsigned short f2bf(float f) {
  union { float f; unsigned u; } x; x.f = f;
  unsigned r = x.u + 0x7fffu + ((x.u >> 16) & 1u);
  return (unsigned short)(r >> 16);
}
__device__ __forceinline__ float bf2f(unsigned short h) {
  union { unsigned u; float f; } x; x.u = ((unsigned)h) << 16;
  return x.f;
}

// staging: two independent BK=32 panels (proven conflict-free layout);
// epi: 128x136 bf16 tile for coalesced write-out (aliases staging after loop)
union SmemU {
  struct { unsigned short A[2][4096]; unsigned short B[2][4096]; } st;  // 32 KB
  unsigned short epi[128 * 136];                                        // 34816 B
};

// ---------------------------------------------------------------------------
// Unified NT bf16 GEMM: A [M][K] k-contig, B [N][K] k-contig, 128x128 tile,
// BK=64 (2 panels), 256 thr = 4 waves, 4x4 of mfma_f32_16x16x32_bf16 / wave.
//   MODE_QKV: z picks B slice + bias + out; z==2 writes v TRANSPOSED [B][D][S]
//   MODE_S:   out bf16 = exp(acc*scale), row exp-sums atomicAdd'ed into lsum
//   MODE_PV:  out fp32 = acc / lsum[row]
// Grid swizzled in-kernel: XCD-aware 4x4 block squares. Requires
// gridDim.x%4==0, gridDim.y%4==0, total blocks %128==0.
//
// PAD (R6): extra dead LDS to tune blocks/CU. PAD=0 -> 34816 B -> 4 blocks/CU
// (S: 1024 blocks = exactly 1.0 fill). PAD=18432 -> 53248 B -> 3 blocks/CU
// (QKV: 1536 blocks = exactly 2.0 fills of 768 slots instead of 1.5 of 1024;
// R0 counters showed QKV per-tile rate is the fastest of the three GEMMs --
// weights L2-resident -- so its wall time was fill-quantization-bound).
// ---------------------------------------------------------------------------
template<int MODE, int PAD = 0>
__global__ __launch_bounds__(256, 4)
void gemm_nt(const unsigned short* __restrict__ A,
             const unsigned short* __restrict__ Bmat,
             const float* __restrict__ b0, const float* __restrict__ b1,
             const float* __restrict__ b2,
             unsigned short* __restrict__ O0, unsigned short* __restrict__ O1,
             unsigned short* __restrict__ O2,
             float* __restrict__ Of, float* __restrict__ lsum,
             int M, int N, int K, long aZ, long bZ, long cZ, float scale)
{
  __shared__ SmemU smem;
  __shared__ char lds_pad[PAD ? PAD : 1];
  if (PAD) {
    // opaque use: keep the allocation without touching it on any hot path
    asm volatile("" :: "v"(&lds_pad[0]));
  }

  const int tid = threadIdx.x;
  const int wave = tid >> 6, lane = tid & 63;
  const int wm = wave >> 1, wn = wave & 1;
  const int quad = lane >> 4, l16 = lane & 15;

  // ---- XCD-aware 4x4-square swizzle ----
  const int gx = gridDim.x, gy = gridDim.y;
  int z, bm, bn;
  {
    int f = (blockIdx.z * gy + blockIdx.y) * gx + blockIdx.x;
    int T = gx * gy * (int)gridDim.z;
    int nsq = T >> 7;                 // 4x4-squares per XCD
    int xcd = f & 7, i = f >> 3;
    int sq = xcd * nsq + (i >> 4);
    int w = i & 15;
    int spz = (gx >> 2) * (gy >> 2);  // squares per z-slice
    z = sq / spz;
    int sqr = sq - z * spz;
    int sqm = sqr / (gx >> 2), sqn = sqr - sqm * (gx >> 2);
    bm = (sqm * 4 + (w >> 2)) * 128;
    bn = (sqn * 4 + (w & 3)) * 128;
  }

  const unsigned short* Ap = (MODE == MODE_QKV) ? A : (A + (long)z * aZ);
  const unsigned short* Bp = Bmat + (long)z * bZ;

  floatx4 acc[4][4];
  #pragma unroll
  for (int i = 0; i < 4; i++)
    #pragma unroll
    for (int j = 0; j < 4; j++)
      acc[i][j] = (floatx4){0.f, 0.f, 0.f, 0.f};

  char* asb = (char*)&smem.st.A[0][0] + wave * 1024;
  char* bsb = (char*)&smem.st.B[0][0] + wave * 1024;

  for (int k0 = 0; k0 < K; k0 += 64) {
    #pragma unroll
    for (int p = 0; p < 2; p++) {
      #pragma unroll
      for (int h = 0; h < 2; h++) {
        int flat = tid + h * 256;        // 16B-chunk index within panel
        int r = flat >> 2, c = (flat & 3) << 3;
        async16(Ap + (long)(bm + r) * K + k0 + p * 32 + c,
                asb + p * 8192 + h * 4096);
        async16(Bp + (long)(bn + r) * K + k0 + p * 32 + c,
                bsb + p * 8192 + h * 4096);
      }
    }
    __syncthreads();

    #pragma unroll
    for (int ks = 0; ks < 2; ks++) {
      short8 afr[4], bfr[4];
      #pragma unroll
      for (int i = 0; i < 4; i++)
        afr[i] = *(const short8*)&smem.st.A[ks][(wm * 64 + i * 16 + l16) * 32 + quad * 8];
      #pragma unroll
      for (int i = 0; i < 4; i++)
        bfr[i] = *(const short8*)&smem.st.B[ks][(wn * 64 + i * 16 + l16) * 32 + quad * 8];
      #pragma unroll
      for (int mi = 0; mi < 4; mi++)
        #pragma unroll
        for (int ni = 0; ni < 4; ni++)
          acc[mi][ni] = __builtin_amdgcn_mfma_f32_16x16x32_bf16(
              afr[mi], bfr[ni], acc[mi][ni], 0, 0, 0);
    }
    __syncthreads();
  }

  // ---- epilogue; C/D layout: col=lane&15, row=quad*4+reg ----
  if (MODE == MODE_PV) {
    // fp32 direct stores, normalized by the row's exp-sum
    #pragma unroll
    for (int mi = 0; mi < 4; mi++) {
      int row0 = bm + wm * 64 + mi * 16 + quad * 4;
      float inv[4];
      #pragma unroll
      for (int r = 0; r < 4; r++)
        inv[r] = 1.0f / lsum[(long)z * M + row0 + r];
      #pragma unroll
      for (int ni = 0; ni < 4; ni++) {
        int col = bn + wn * 64 + ni * 16 + l16;
        #pragma unroll
        for (int r = 0; r < 4; r++)
          Of[(long)z * cZ + (long)(row0 + r) * N + col] = acc[mi][ni][r] * inv[r];
      }
    }
    return;
  }

  const bool vtrans = (MODE == MODE_QKV) && (z == 2);
  float bi[4];
  if (MODE == MODE_QKV) {
    const float* bias = (z == 0) ? b0 : ((z == 1) ? b1 : b2);
    #pragma unroll
    for (int ni = 0; ni < 4; ni++) bi[ni] = bias[bn + wn * 64 + ni * 16 + l16];
  }

  // stage bf16 tile into LDS (normal: epi[row][col]; vtrans: epi[col][row])
  #pragma unroll
  for (int ni = 0; ni < 4; ni++) {
    int col = wn * 64 + ni * 16 + l16;
    float bb = (MODE == MODE_QKV) ? bi[ni] : 0.f;
    #pragma unroll
    for (int mi = 0; mi < 4; mi++) {
      int row0 = wm * 64 + mi * 16 + quad * 4;
      if (MODE == MODE_S) {
        #pragma unroll
        for (int r = 0; r < 4; r++)
          smem.epi[(row0 + r) * 136 + col] = f2bf(__expf(acc[mi][ni][r] * scale));
      } else if (!vtrans) {
        #pragma unroll
        for (int r = 0; r < 4; r++)
          smem.epi[(row0 + r) * 136 + col] = f2bf(acc[mi][ni][r] + bb);
      } else {
        #pragma unroll
        for (int r = 0; r < 4; r += 2) {
          unsigned lo = f2bf(acc[mi][ni][r] + bb);
          unsigned hi = f2bf(acc[mi][ni][r + 1] + bb);
          *(unsigned*)&smem.epi[col * 136 + row0 + r] = lo | (hi << 16);
        }
      }
    }
  }
  __syncthreads();

  // coalesced 16B write-out (+ row-sum atomics for MODE_S)
  #pragma unroll
  for (int i = 0; i < 8; i++) {
    int flat = i * 2048 + tid * 8;
    int rr = flat >> 7, cc = flat & 127;
    short8 vline = *(const short8*)&smem.epi[rr * 136 + cc];
    if (MODE == MODE_S) {
      union { short8 v; unsigned short u[8]; } t; t.v = vline;
      float s8 = 0.f;
      #pragma unroll
      for (int j = 0; j < 8; j++) s8 += bf2f(t.u[j]);
      s8 += __shfl_xor(s8, 1);
      s8 += __shfl_xor(s8, 2);
      s8 += __shfl_xor(s8, 4);
      s8 += __shfl_xor(s8, 8);
      if ((lane & 15) == 0) atomicAdd(&lsum[(long)z * M + bm + rr], s8);
      *(short8*)&O0[(long)z * cZ + (long)(bm + rr) * N + bn + cc] = vline;
    } else if (!vtrans) {
      unsigned short* O = (z == 0) ? O0 : O1;
      *(short8*)&O[(long)(bm + rr) * N + bn + cc] = vline;
    } else {
      int bb = bm >> 11, s0 = bm & 2047;  // S=2048, tiles don't straddle batch
      *(short8*)&O2[(long)bb * (1024L * 2048) + (long)(bn + rr) * 2048 + s0 + cc] = vline;
    }
  }
}

// Fused prep: [0,4096) x fp32->bf16; [4096,7168) W transpose->bf16;
// [7168,7200) zero the 8192-float lsum buffer.
__global__ __launch_bounds__(256)
void prep_kernel(const float* __restrict__ x, unsigned short* __restrict__ xb,
                 const float* __restrict__ W0, const float* __restrict__ W1,
                 const float* __restrict__ W2, unsigned short* __restrict__ Wt,
                 float* __restrict__ lsum) {
  int blk = blockIdx.x;
  if (blk < 4096) {
    long i = ((long)blk * 256 + threadIdx.x) * 8;
    float4 a = *(const float4*)(x + i);
    float4 b = *(const float4*)(x + i + 4);
    union { int4 v; unsigned short u[8]; } t;
    t.u[0] = f2bf(a.x); t.u[1] = f2bf(a.y); t.u[2] = f2bf(a.z); t.u[3] = f2bf(a.w);
    t.u[4] = f2bf(b.x); t.u[5] = f2bf(b.y); t.u[6] = f2bf(b.z); t.u[7] = f2bf(b.w);
    *(int4*)(xb + i) = t.v;
  } else if (blk < 7168) {
    __shared__ float tile[32][33];
    int tt = blk - 4096;
    int zz = tt >> 10, rem = tt & 1023;
    int kb = (rem >> 5) * 32, nb = (rem & 31) * 32;
    const float* W = (zz == 0) ? W0 : ((zz == 1) ? W1 : W2);
    unsigned short* O = Wt + (long)zz * 1024 * 1024;
    int t = threadIdx.x, tr = t >> 5, tc = t & 31;
    #pragma unroll
    for (int i = 0; i < 4; i++)
      tile[tr + i * 8][tc] = W[(long)(kb + tr + i * 8) * 1024 + nb + tc];
    __syncthreads();
    #pragma unroll
    for (int i = 0; i < 4; i++)
      O[(long)(nb + tr + i * 8) * 1024 + kb + tc] = f2bf(tile[tc][tr + i * 8]);
  } else {
    int i = (blk - 7168) * 256 + threadIdx.x;  // 32*256 = 8192 floats
    lsum[i] = 0.f;
  }
}

extern "C" void kernel_launch(void* const* d_in, const int* in_sizes, int n_in,
                              void* d_out, int out_size, void* d_ws, size_t ws_size,
                              hipStream_t stream) {
  const float* x  = (const float*)d_in[0];
  const float* Wq = (const float*)d_in[1];
  const float* bq = (const float*)d_in[2];
  const float* Wk = (const float*)d_in[3];
  const float* bk = (const float*)d_in[4];
  const float* Wv = (const float*)d_in[5];
  const float* bv = (const float*)d_in[6];
  float* out = (float*)d_out;

  const int B = 4, S = 2048, D = 1024;
  const int M = B * S;
  const float scale = 0.03125f;  // 1/sqrt(1024)

  // xb (16 MiB) + Wt (6 MiB) borrow d_out's first 22 MiB; dead before the
  // PV GEMM overwrites all of d_out.
  unsigned short* xb = (unsigned short*)d_out;
  unsigned short* Wt = xb + (size_t)M * D;
  unsigned short* q  = (unsigned short*)d_ws;
  unsigned short* k  = q + (size_t)M * D;
  unsigned short* vT = k + (size_t)M * D;
  unsigned short* P  = vT + (size_t)M * D;

  size_t need_full = ((size_t)3 * M * D + (size_t)B * S * S) * sizeof(unsigned short)
                   + (size_t)M * sizeof(float);
  const bool full = (ws_size >= need_full);
  float* lsum = full ? (float*)(P + (size_t)B * S * S)
                     : (float*)(P + (size_t)S * S);

  prep_kernel<<<7200, 256, 0, stream>>>(x, xb, Wq, Wk, Wv, Wt, lsum);

  // PAD=18432 -> 53248 B LDS -> 3 blocks/CU -> 1536 blocks = exactly 2 fills
  gemm_nt<MODE_QKV, 18432><<<dim3(D / 128, M / 128, 3), 256, 0, stream>>>(
      xb, Wt, bq, bk, bv, q, k, vT, nullptr, nullptr,
      M, D, D, 0, (long)D * D, 0, 1.0f);

  if (full) {
    gemm_nt<MODE_S><<<dim3(S / 128, S / 128, B), 256, 0, stream>>>(
        q, k, nullptr, nullptr, nullptr, P, nullptr, nullptr, nullptr, lsum,
        S, S, D, (long)S * D, (long)S * D, (long)S * S, scale);
    gemm_nt<MODE_PV><<<dim3(D / 128, S / 128, B), 256, 0, stream>>>(
        P, vT, nullptr, nullptr, nullptr, nullptr, nullptr, nullptr, out, lsum,
        S, D, S, (long)S * S, (long)D * S, (long)S * D, 1.0f);
  } else {
    for (int b = 0; b < B; b++) {
      const unsigned short* qb = q + (size_t)b * S * D;
      const unsigned short* kb = k + (size_t)b * S * D;
      const unsigned short* vb = vT + (size_t)b * S * D;
      float* ob = out + (size_t)b * S * D;
      gemm_nt<MODE_S><<<dim3(S / 128, S / 128, 1), 256, 0, stream>>>(
          qb, kb, nullptr, nullptr, nullptr, P, nullptr, nullptr, nullptr,
          lsum + (size_t)b * S,
          S, S, D, 0, 0, 0, scale);
      gemm_nt<MODE_PV><<<dim3(D / 128, S / 128, 1), 256, 0, stream>>>(
          P, vb, nullptr, nullptr, nullptr, nullptr, nullptr, nullptr, ob,
          lsum + (size_t)b * S,
          S, D, S, 0, 0, 0, 1.0f);
    }
  }
}

// Round 8
// 232.840 us; speedup vs baseline: 1.2682x; 1.0260x over previous
//
#include <hip/hip_runtime.h>

#define MODE_QKV 0
#define MODE_S   1
#define MODE_PV  2

typedef __attribute__((ext_vector_type(8))) short short8;
typedef __attribute__((ext_vector_type(4))) float floatx4;

typedef const unsigned __attribute__((address_space(1)))* gp_t;
typedef unsigned __attribute__((address_space(3)))* lp_t;

__device__ __forceinline__ void async16(const void* g, void* l) {
  // stages 16B/lane: LDS dest = wave-uniform base + lane*16
  __builtin_amdgcn_global_load_lds((gp_t)g, (lp_t)l, 16, 0, 0);
}

__device__ __forceinline__ void bar_raw() {
  asm volatile("s_barrier" ::: "memory");
}

__device__ __forceinline__ unsigned short f2bf(float f) {
  union { float f; unsigned u; } x; x.f = f;
  unsigned r = x.u + 0x7fffu + ((x.u >> 16) & 1u);
  return (unsigned short)(r >> 16);
}
__device__ __forceinline__ float bf2f(unsigned short h) {
  union { unsigned u; float f; } x; x.u = ((unsigned)h) << 16;
  return x.f;
}

// ===========================================================================
// gemm256: 256x256 8-phase kernel (R4 version, verbatim). Used ONLY for
// MODE_S: its 256-block grid = exactly 1.0 fill at 1 block/CU, where it
// measured -3.5 us vs the legacy kernel (R2/R3/R4 total-time deltas).
// QKV (384 blocks = 1.5 fills) and PV (128 blocks = 0.5 fill) measured
// +10/+15 us on this kernel -- fill quantization at 1 block/CU granularity
// -- so they stay on the legacy 4-blocks/CU 128^2 kernel.
// ===========================================================================

__device__ __forceinline__ void stage_half(const unsigned short* gp, long rowbase,
                                           int ldk, int kb, char* region,
                                           int wave, int lane) {
  const int rs = lane >> 3;                    // row within 8-row group
  const int kc = ((lane & 7) ^ rs) << 3;       // pre-swizzled k-chunk (elems)
  #pragma unroll
  for (int h = 0; h < 2; h++) {
    const int rr = (h * 8 + wave) * 8 + rs;    // row within 128-row half
    async16(gp + (rowbase + rr) * (long)ldk + kb + kc,
            region + (h * 8 + wave) * 1024);
  }
}

__device__ __forceinline__ short8 frag(const char* region, int hr, int ks, int quad) {
  // logical chunk = ks*4+quad; physical = chunk ^ (hr&7); 16B chunks, 128B rows
  return *(const short8*)(region + hr * 128 + ((((ks << 2) | quad) ^ (hr & 7)) << 4));
}

#define MFMA_QUAD(MH, NH)                                                    \
  do {                                                                       \
    _Pragma("unroll")                                                        \
    for (int mi_ = 0; mi_ < 4; mi_++) {                                      \
      _Pragma("unroll")                                                      \
      for (int jj_ = 0; jj_ < 2; jj_++) {                                    \
        _Pragma("unroll")                                                    \
        for (int ks_ = 0; ks_ < 2; ks_++) {                                  \
          acc[MH][mi_][NH][jj_] = __builtin_amdgcn_mfma_f32_16x16x32_bf16(   \
              a[mi_][ks_], b[NH][jj_][ks_], acc[MH][mi_][NH][jj_], 0, 0, 0); \
        }                                                                    \
      }                                                                      \
    }                                                                        \
  } while (0)

template<int MODE>
__global__ __launch_bounds__(512, 1)
void gemm256(const unsigned short* __restrict__ A,
             const unsigned short* __restrict__ Bmat,
             const float* __restrict__ b0, const float* __restrict__ b1,
             const float* __restrict__ b2,
             unsigned short* __restrict__ O0, unsigned short* __restrict__ O1,
             unsigned short* __restrict__ O2, float* __restrict__ Of,
             float* __restrict__ lsum,
             int M, int N, int K, long aZ, long bZ, long cZ, float scale)
{
  __shared__ __attribute__((aligned(128))) char lds[131072];

  const int tid = threadIdx.x;
  const int wave = tid >> 6, lane = tid & 63;
  const int wm = wave >> 2, wn = wave & 3;
  const int quad = lane >> 4, l16 = lane & 15;

  // ---- XCD-aware 4x4-square swizzle (requires total blocks % 128 == 0) ----
  const int gx = gridDim.x, gy = gridDim.y;
  int z, bm, bn;
  {
    int f = (blockIdx.z * gy + blockIdx.y) * gx + blockIdx.x;
    int T = gx * gy * (int)gridDim.z;
    int nsq = T >> 7;
    int xcd = f & 7, i = f >> 3;
    int sq = xcd * nsq + (i >> 4);
    int w = i & 15;
    int spz = (gx >> 2) * (gy >> 2);
    z = sq / spz;
    int sqr = sq - z * spz;
    int sqm = sqr / (gx >> 2), sqn = sqr - sqm * (gx >> 2);
    bm = (sqm * 4 + (w >> 2)) * 256;
    bn = (sqn * 4 + (w & 3)) * 256;
  }

  const unsigned short* Ap = (MODE == MODE_QKV) ? A : (A + (long)z * aZ);
  const unsigned short* Bp = Bmat + (long)z * bZ;

  const int NT = K >> 6;

  // region offsets within a buffer: A0=0, A1=16384, B0=32768, B1=49152
  stage_half(Ap, bm,       K, 0,  lds +     0, wave, lane);
  stage_half(Bp, bn,       K, 0,  lds + 32768, wave, lane);
  stage_half(Bp, bn + 128, K, 0,  lds + 49152, wave, lane);
  stage_half(Ap, bm + 128, K, 0,  lds + 16384, wave, lane);
  stage_half(Ap, bm,       K, 64, lds + 65536 +     0, wave, lane);
  stage_half(Bp, bn,       K, 64, lds + 65536 + 32768, wave, lane);
  stage_half(Bp, bn + 128, K, 64, lds + 65536 + 49152, wave, lane);
  asm volatile("s_waitcnt vmcnt(6)" ::: "memory");
  bar_raw();

  floatx4 acc[2][4][2][2];   // [mh][mi][nh][jj]
  #pragma unroll
  for (int p = 0; p < 2; p++)
    #pragma unroll
    for (int q2 = 0; q2 < 4; q2++)
      #pragma unroll
      for (int r = 0; r < 2; r++)
        #pragma unroll
        for (int s = 0; s < 2; s++)
          acc[p][q2][r][s] = (floatx4){0.f, 0.f, 0.f, 0.f};

  short8 a[4][2];      // current mh's A frags [mi][ks]
  short8 b[2][2][2];   // both nh's B frags    [nh][jj][ks]

  for (int j = 0; j < NT; j++) {
    char* bufc = lds + ((j & 1) << 16);
    char* bufn = lds + (((j + 1) & 1) << 16);
    const bool lp = (j + 2 >= NT);
    const int kn  = (j + 1) << 6;
    const int kn2 = (j + 2) << 6;

    // ---- phase 0 : q(0,0) ----
    #pragma unroll
    for (int mi = 0; mi < 4; mi++)
      #pragma unroll
      for (int ks = 0; ks < 2; ks++)
        a[mi][ks] = frag(bufc, wm * 64 + mi * 16 + l16, ks, quad);
    #pragma unroll
    for (int jj = 0; jj < 2; jj++)
      #pragma unroll
      for (int ks = 0; ks < 2; ks++)
        b[0][jj][ks] = frag(bufc + 32768, wn * 32 + jj * 16 + l16, ks, quad);
    if (j + 1 < NT)
      stage_half(Ap, bm + 128, K, kn, bufn + 16384, wave, lane);   // Ah1(j+1)
    bar_raw();
    asm volatile("s_waitcnt lgkmcnt(0)" ::: "memory");
    __builtin_amdgcn_s_setprio(1);
    MFMA_QUAD(0, 0);
    __builtin_amdgcn_s_setprio(0);
    bar_raw();

    // ---- phase 1 : q(0,1) ----
    #pragma unroll
    for (int jj = 0; jj < 2; jj++)
      #pragma unroll
      for (int ks = 0; ks < 2; ks++)
        b[1][jj][ks] = frag(bufc + 49152, wn * 32 + jj * 16 + l16, ks, quad);
    if (!lp)
      stage_half(Ap, bm, K, kn2, bufc, wave, lane);                // Ah0(j+2)
    bar_raw();
    asm volatile("s_waitcnt lgkmcnt(0)" ::: "memory");
    __builtin_amdgcn_s_setprio(1);
    MFMA_QUAD(0, 1);
    __builtin_amdgcn_s_setprio(0);
    bar_raw();

    // ---- phase 2 : q(1,0) ----
    #pragma unroll
    for (int mi = 0; mi < 4; mi++)
      #pragma unroll
      for (int ks = 0; ks < 2; ks++)
        a[mi][ks] = frag(bufc + 16384, wm * 64 + mi * 16 + l16, ks, quad);
    if (!lp)
      stage_half(Bp, bn, K, kn2, bufc + 32768, wave, lane);        // Bh0(j+2)
    bar_raw();
    asm volatile("s_waitcnt lgkmcnt(0)" ::: "memory");
    __builtin_amdgcn_s_setprio(1);
    MFMA_QUAD(1, 0);
    __builtin_amdgcn_s_setprio(0);
    bar_raw();

    // ---- phase 3 : q(1,1) ----
    if (!lp) {
      stage_half(Bp, bn + 128, K, kn2, bufc + 49152, wave, lane);  // Bh1(j+2)
      asm volatile("s_waitcnt vmcnt(6)" ::: "memory");
    } else {
      asm volatile("s_waitcnt vmcnt(0)" ::: "memory");
    }
    bar_raw();
    __builtin_amdgcn_s_setprio(1);
    MFMA_QUAD(1, 1);
    __builtin_amdgcn_s_setprio(0);
    bar_raw();
  }

  if (MODE == MODE_PV) {
    #pragma unroll
    for (int mh = 0; mh < 2; mh++)
      #pragma unroll
      for (int mi = 0; mi < 4; mi++) {
        const int row0 = bm + mh * 128 + wm * 64 + mi * 16 + quad * 4;
        float inv[4];
        #pragma unroll
        for (int r = 0; r < 4; r++)
          inv[r] = 1.0f / lsum[(long)z * M + row0 + r];
        #pragma unroll
        for (int nh = 0; nh < 2; nh++)
          #pragma unroll
          for (int jj = 0; jj < 2; jj++) {
            const int col = bn + nh * 128 + wn * 32 + jj * 16 + l16;
            #pragma unroll
            for (int r = 0; r < 4; r++)
              Of[(long)z * cZ + (long)(row0 + r) * N + col] =
                  acc[mh][mi][nh][jj][r] * inv[r];
          }
      }
    return;
  }

  const bool vtrans = (MODE == MODE_QKV) && (z == 2);
  float bi[2][2];
  if (MODE == MODE_QKV) {
    const float* bias = (z == 0) ? b0 : ((z == 1) ? b1 : b2);
    #pragma unroll
    for (int nh = 0; nh < 2; nh++)
      #pragma unroll
      for (int jj = 0; jj < 2; jj++)
        bi[nh][jj] = bias[bn + nh * 128 + wn * 32 + jj * 16 + l16];
  }

  unsigned short* epi = (unsigned short*)lds;
  #pragma unroll
  for (int mh = 0; mh < 2; mh++) {
    #pragma unroll
    for (int mi = 0; mi < 4; mi++) {
      const int r0 = wm * 64 + mi * 16 + quad * 4;
      #pragma unroll
      for (int nh = 0; nh < 2; nh++)
        #pragma unroll
        for (int jj = 0; jj < 2; jj++) {
          const int col = nh * 128 + wn * 32 + jj * 16 + l16;
          if (MODE == MODE_S) {
            #pragma unroll
            for (int r = 0; r < 4; r++)
              epi[(r0 + r) * 264 + col] = f2bf(__expf(acc[mh][mi][nh][jj][r] * scale));
          } else if (!vtrans) {
            #pragma unroll
            for (int r = 0; r < 4; r++)
              epi[(r0 + r) * 264 + col] = f2bf(acc[mh][mi][nh][jj][r] + bi[nh][jj]);
          } else {
            #pragma unroll
            for (int r = 0; r < 4; r += 2) {
              unsigned lo = f2bf(acc[mh][mi][nh][jj][r] + bi[nh][jj]);
              unsigned hi = f2bf(acc[mh][mi][nh][jj][r + 1] + bi[nh][jj]);
              *(unsigned*)&epi[col * 136 + r0 + r] = lo | (hi << 16);
            }
          }
        }
    }
    __syncthreads();

    if (!vtrans) {
      #pragma unroll
      for (int it = 0; it < 8; it++) {
        int flat = it * 4096 + tid * 8;
        int rr = flat >> 8, cc = flat & 255;
        short8 vline = *(const short8*)&epi[rr * 264 + cc];
        long grow = bm + mh * 128 + rr;
        if (MODE == MODE_S) {
          union { short8 v; unsigned short u[8]; } t; t.v = vline;
          float s8 = 0.f;
          #pragma unroll
          for (int jq = 0; jq < 8; jq++) s8 += bf2f(t.u[jq]);
          s8 += __shfl_xor(s8, 1);
          s8 += __shfl_xor(s8, 2);
          s8 += __shfl_xor(s8, 4);
          s8 += __shfl_xor(s8, 8);
          s8 += __shfl_xor(s8, 16);
          if ((lane & 31) == 0) atomicAdd(&lsum[(long)z * M + grow], s8);
          *(short8*)&O0[(long)z * cZ + grow * N + bn + cc] = vline;
        } else {
          unsigned short* O = (z == 0) ? O0 : O1;
          *(short8*)&O[grow * N + bn + cc] = vline;
        }
      }
    } else {
      int bb2 = bm >> 11, s0 = bm & 2047;
      #pragma unroll
      for (int it = 0; it < 8; it++) {
        int flat = it * 4096 + tid * 8;
        int dd = flat >> 7, ss = flat & 127;
        short8 vline = *(const short8*)&epi[dd * 136 + ss];
        *(short8*)&O2[(long)bb2 * (1024L * 2048) + (long)(bn + dd) * 2048 + s0 + mh * 128 + ss] = vline;
      }
    }
    if (mh == 0) __syncthreads();
  }
}

// ===========================================================================
// Legacy 128x128 kernel: best measured for QKV (65.2 us) and PV.
// R7 lesson: it NEEDS 4 blocks/CU (16 waves) of TLP -- 3/CU was 7% slower
// per block. PAD removed.
// ===========================================================================

union SmemU {
  struct { unsigned short A[2][4096]; unsigned short B[2][4096]; } st;  // 32 KB
  unsigned short epi[128 * 136];                                        // 34816 B
};

template<int MODE>
__global__ __launch_bounds__(256, 4)
void gemm_nt(const unsigned short* __restrict__ A,
             const unsigned short* __restrict__ Bmat,
             const float* __restrict__ b0, const float* __restrict__ b1,
             const float* __restrict__ b2,
             unsigned short* __restrict__ O0, unsigned short* __restrict__ O1,
             unsigned short* __restrict__ O2,
             float* __restrict__ Of, float* __restrict__ lsum,
             int M, int N, int K, long aZ, long bZ, long cZ, float scale)
{
  __shared__ SmemU smem;

  const int tid = threadIdx.x;
  const int wave = tid >> 6, lane = tid & 63;
  const int wm = wave >> 1, wn = wave & 1;
  const int quad = lane >> 4, l16 = lane & 15;

  const int gx = gridDim.x, gy = gridDim.y;
  int z, bm, bn;
  {
    int f = (blockIdx.z * gy + blockIdx.y) * gx + blockIdx.x;
    int T = gx * gy * (int)gridDim.z;
    int nsq = T >> 7;
    int xcd = f & 7, i = f >> 3;
    int sq = xcd * nsq + (i >> 4);
    int w = i & 15;
    int spz = (gx >> 2) * (gy >> 2);
    z = sq / spz;
    int sqr = sq - z * spz;
    int sqm = sqr / (gx >> 2), sqn = sqr - sqm * (gx >> 2);
    bm = (sqm * 4 + (w >> 2)) * 128;
    bn = (sqn * 4 + (w & 3)) * 128;
  }

  const unsigned short* Ap = (MODE == MODE_QKV) ? A : (A + (long)z * aZ);
  const unsigned short* Bp = Bmat + (long)z * bZ;

  floatx4 acc[4][4];
  #pragma unroll
  for (int i = 0; i < 4; i++)
    #pragma unroll
    for (int j = 0; j < 4; j++)
      acc[i][j] = (floatx4){0.f, 0.f, 0.f, 0.f};

  char* asb = (char*)&smem.st.A[0][0] + wave * 1024;
  char* bsb = (char*)&smem.st.B[0][0] + wave * 1024;

  for (int k0 = 0; k0 < K; k0 += 64) {
    #pragma unroll
    for (int p = 0; p < 2; p++) {
      #pragma unroll
      for (int h = 0; h < 2; h++) {
        int flat = tid + h * 256;
        int r = flat >> 2, c = (flat & 3) << 3;
        async16(Ap + (long)(bm + r) * K + k0 + p * 32 + c,
                asb + p * 8192 + h * 4096);
        async16(Bp + (long)(bn + r) * K + k0 + p * 32 + c,
                bsb + p * 8192 + h * 4096);
      }
    }
    __syncthreads();

    #pragma unroll
    for (int ks = 0; ks < 2; ks++) {
      short8 afr[4], bfr[4];
      #pragma unroll
      for (int i = 0; i < 4; i++)
        afr[i] = *(const short8*)&smem.st.A[ks][(wm * 64 + i * 16 + l16) * 32 + quad * 8];
      #pragma unroll
      for (int i = 0; i < 4; i++)
        bfr[i] = *(const short8*)&smem.st.B[ks][(wn * 64 + i * 16 + l16) * 32 + quad * 8];
      #pragma unroll
      for (int mi = 0; mi < 4; mi++)
        #pragma unroll
        for (int ni = 0; ni < 4; ni++)
          acc[mi][ni] = __builtin_amdgcn_mfma_f32_16x16x32_bf16(
              afr[mi], bfr[ni], acc[mi][ni], 0, 0, 0);
    }
    __syncthreads();
  }

  if (MODE == MODE_PV) {
    #pragma unroll
    for (int mi = 0; mi < 4; mi++) {
      int row0 = bm + wm * 64 + mi * 16 + quad * 4;
      float inv[4];
      #pragma unroll
      for (int r = 0; r < 4; r++)
        inv[r] = 1.0f / lsum[(long)z * M + row0 + r];
      #pragma unroll
      for (int ni = 0; ni < 4; ni++) {
        int col = bn + wn * 64 + ni * 16 + l16;
        #pragma unroll
        for (int r = 0; r < 4; r++)
          Of[(long)z * cZ + (long)(row0 + r) * N + col] = acc[mi][ni][r] * inv[r];
      }
    }
    return;
  }

  const bool vtrans = (MODE == MODE_QKV) && (z == 2);
  float bi[4];
  if (MODE == MODE_QKV) {
    const float* bias = (z == 0) ? b0 : ((z == 1) ? b1 : b2);
    #pragma unroll
    for (int ni = 0; ni < 4; ni++) bi[ni] = bias[bn + wn * 64 + ni * 16 + l16];
  }

  #pragma unroll
  for (int ni = 0; ni < 4; ni++) {
    int col = wn * 64 + ni * 16 + l16;
    float bb = (MODE == MODE_QKV) ? bi[ni] : 0.f;
    #pragma unroll
    for (int mi = 0; mi < 4; mi++) {
      int row0 = wm * 64 + mi * 16 + quad * 4;
      if (MODE == MODE_S) {
        #pragma unroll
        for (int r = 0; r < 4; r++)
          smem.epi[(row0 + r) * 136 + col] = f2bf(__expf(acc[mi][ni][r] * scale));
      } else if (!vtrans) {
        #pragma unroll
        for (int r = 0; r < 4; r++)
          smem.epi[(row0 + r) * 136 + col] = f2bf(acc[mi][ni][r] + bb);
      } else {
        #pragma unroll
        for (int r = 0; r < 4; r += 2) {
          unsigned lo = f2bf(acc[mi][ni][r] + bb);
          unsigned hi = f2bf(acc[mi][ni][r + 1] + bb);
          *(unsigned*)&smem.epi[col * 136 + row0 + r] = lo | (hi << 16);
        }
      }
    }
  }
  __syncthreads();

  #pragma unroll
  for (int i = 0; i < 8; i++) {
    int flat = i * 2048 + tid * 8;
    int rr = flat >> 7, cc = flat & 127;
    short8 vline = *(const short8*)&smem.epi[rr * 136 + cc];
    if (MODE == MODE_S) {
      union { short8 v; unsigned short u[8]; } t; t.v = vline;
      float s8 = 0.f;
      #pragma unroll
      for (int j = 0; j < 8; j++) s8 += bf2f(t.u[j]);
      s8 += __shfl_xor(s8, 1);
      s8 += __shfl_xor(s8, 2);
      s8 += __shfl_xor(s8, 4);
      s8 += __shfl_xor(s8, 8);
      if ((lane & 15) == 0) atomicAdd(&lsum[(long)z * M + bm + rr], s8);
      *(short8*)&O0[(long)z * cZ + (long)(bm + rr) * N + bn + cc] = vline;
    } else if (!vtrans) {
      unsigned short* O = (z == 0) ? O0 : O1;
      *(short8*)&O[(long)(bm + rr) * N + bn + cc] = vline;
    } else {
      int bb = bm >> 11, s0 = bm & 2047;
      *(short8*)&O2[(long)bb * (1024L * 2048) + (long)(bn + rr) * 2048 + s0 + cc] = vline;
    }
  }
}

// Fused prep: [0,4096) x fp32->bf16; [4096,7168) W transpose->bf16;
// [7168,7200) zero the 8192-float lsum buffer.
__global__ __launch_bounds__(256)
void prep_kernel(const float* __restrict__ x, unsigned short* __restrict__ xb,
                 const float* __restrict__ W0, const float* __restrict__ W1,
                 const float* __restrict__ W2, unsigned short* __restrict__ Wt,
                 float* __restrict__ lsum) {
  int blk = blockIdx.x;
  if (blk < 4096) {
    long i = ((long)blk * 256 + threadIdx.x) * 8;
    float4 a = *(const float4*)(x + i);
    float4 b = *(const float4*)(x + i + 4);
    union { int4 v; unsigned short u[8]; } t;
    t.u[0] = f2bf(a.x); t.u[1] = f2bf(a.y); t.u[2] = f2bf(a.z); t.u[3] = f2bf(a.w);
    t.u[4] = f2bf(b.x); t.u[5] = f2bf(b.y); t.u[6] = f2bf(b.z); t.u[7] = f2bf(b.w);
    *(int4*)(xb + i) = t.v;
  } else if (blk < 7168) {
    __shared__ float tile[32][33];
    int tt = blk - 4096;
    int zz = tt >> 10, rem = tt & 1023;
    int kb = (rem >> 5) * 32, nb = (rem & 31) * 32;
    const float* W = (zz == 0) ? W0 : ((zz == 1) ? W1 : W2);
    unsigned short* O = Wt + (long)zz * 1024 * 1024;
    int t = threadIdx.x, tr = t >> 5, tc = t & 31;
    #pragma unroll
    for (int i = 0; i < 4; i++)
      tile[tr + i * 8][tc] = W[(long)(kb + tr + i * 8) * 1024 + nb + tc];
    __syncthreads();
    #pragma unroll
    for (int i = 0; i < 4; i++)
      O[(long)(nb + tr + i * 8) * 1024 + kb + tc] = f2bf(tile[tc][tr + i * 8]);
  } else {
    int i = (blk - 7168) * 256 + threadIdx.x;  // 32*256 = 8192 floats
    lsum[i] = 0.f;
  }
}

extern "C" void kernel_launch(void* const* d_in, const int* in_sizes, int n_in,
                              void* d_out, int out_size, void* d_ws, size_t ws_size,
                              hipStream_t stream) {
  const float* x  = (const float*)d_in[0];
  const float* Wq = (const float*)d_in[1];
  const float* bq = (const float*)d_in[2];
  const float* Wk = (const float*)d_in[3];
  const float* bk = (const float*)d_in[4];
  const float* Wv = (const float*)d_in[5];
  const float* bv = (const float*)d_in[6];
  float* out = (float*)d_out;

  const int B = 4, S = 2048, D = 1024;
  const int M = B * S;
  const float scale = 0.03125f;  // 1/sqrt(1024)

  // xb (16 MiB) + Wt (6 MiB) borrow d_out's first 22 MiB; dead before the
  // PV GEMM overwrites all of d_out.
  unsigned short* xb = (unsigned short*)d_out;
  unsigned short* Wt = xb + (size_t)M * D;
  unsigned short* q  = (unsigned short*)d_ws;
  unsigned short* k  = q + (size_t)M * D;
  unsigned short* vT = k + (size_t)M * D;
  unsigned short* P  = vT + (size_t)M * D;

  size_t need_full = ((size_t)3 * M * D + (size_t)B * S * S) * sizeof(unsigned short)
                   + (size_t)M * sizeof(float);
  const bool full = (ws_size >= need_full);
  float* lsum = full ? (float*)(P + (size_t)B * S * S)
                     : (float*)(P + (size_t)S * S);

  prep_kernel<<<7200, 256, 0, stream>>>(x, xb, Wq, Wk, Wv, Wt, lsum);

  // QKV: legacy 128^2 @ 4 blocks/CU (best measured: 65.2 us)
  gemm_nt<MODE_QKV><<<dim3(D / 128, M / 128, 3), 256, 0, stream>>>(
      xb, Wt, bq, bk, bv, q, k, vT, nullptr, nullptr,
      M, D, D, 0, (long)D * D, 0, 1.0f);

  if (full) {
    // S: 256^2 8-phase -- 256 blocks = exact 1.0 fill; measured -3.5 us
    gemm256<MODE_S><<<dim3(S / 256, S / 256, B), 512, 0, stream>>>(
        q, k, nullptr, nullptr, nullptr, P, nullptr, nullptr, nullptr, lsum,
        S, S, D, (long)S * D, (long)S * D, (long)S * S, scale);
    // PV: legacy (256^2 measured +15 us: 0.5 fill)
    gemm_nt<MODE_PV><<<dim3(D / 128, S / 128, B), 256, 0, stream>>>(
        P, vT, nullptr, nullptr, nullptr, nullptr, nullptr, nullptr, out, lsum,
        S, D, S, (long)S * S, (long)D * S, (long)S * D, 1.0f);
  } else {
    for (int b = 0; b < B; b++) {
      const unsigned short* qb = q + (size_t)b * S * D;
      const unsigned short* kb = k + (size_t)b * S * D;
      const unsigned short* vb = vT + (size_t)b * S * D;
      float* ob = out + (size_t)b * S * D;
      gemm_nt<MODE_S><<<dim3(S / 128, S / 128, 1), 256, 0, stream>>>(
          qb, kb, nullptr, nullptr, nullptr, P, nullptr, nullptr, nullptr,
          lsum + (size_t)b * S,
          S, S, D, 0, 0, 0, scale);
      gemm_nt<MODE_PV><<<dim3(D / 128, S / 128, 1), 256, 0, stream>>>(
          P, vb, nullptr, nullptr, nullptr, nullptr, nullptr, nullptr, ob,
          lsum + (size_t)b * S,
          S, D, S, 0, 0, 0, 1.0f);
    }
  }
}

// Round 9
// 224.903 us; speedup vs baseline: 1.3130x; 1.0353x over previous
//
#include <hip/hip_runtime.h>

#define MODE_QKV 0
#define MODE_S   1
#define MODE_PV  2

typedef __attribute__((ext_vector_type(8))) short short8;
typedef __attribute__((ext_vector_type(4))) float floatx4;

typedef const unsigned __attribute__((address_space(1)))* gp_t;
typedef unsigned __attribute__((address_space(3)))* lp_t;

__device__ __forceinline__ void async16(const void* g, void* l) {
  // stages 16B/lane: LDS dest = wave-uniform base + lane*16
  __builtin_amdgcn_global_load_lds((gp_t)g, (lp_t)l, 16, 0, 0);
}

__device__ __forceinline__ void bar_raw() {
  asm volatile("s_barrier" ::: "memory");
}

__device__ __forceinline__ unsigned short f2bf(float f) {
  union { float f; unsigned u; } x; x.f = f;
  unsigned r = x.u + 0x7fffu + ((x.u >> 16) & 1u);
  return (unsigned short)(r >> 16);
}
__device__ __forceinline__ float bf2f(unsigned short h) {
  union { unsigned u; float f; } x; x.u = ((unsigned)h) << 16;
  return x.f;
}

// ===========================================================================
// gemm_qkv (R9): FUSED q/k/v projection. One block computes the 128x128
// output tile for ALL THREE weight matrices: A (xb) is staged to LDS and
// frag-read ONCE, feeding 3 accumulator sets.
//
// Why: legacy QKV is LDS-BW-bound -- 96 KB LDS traffic per 128 MFMA
// (0.75 KB/MFMA) caps MfmaUtil at the measured ~33%. Fused: 192 KB per
// 384 MFMA (0.5 KB/MFMA) = 1.5x better intensity. Also: grid 8x64 = 512
// blocks at 2 blocks/CU = EXACT 1.0 fill (legacy z=3 grid was 1.5 fills),
// and x is HBM-fetched once not 3x.
//
// Budget: acc[3][4][4] floatx4 = 192 VGPR + frags/addr ~= 240; cap 256 via
// launch_bounds(256,2). LDS = 4 panelsets x 16 KB = 64 KB -> 2 blocks/CU.
// SPILL CANARY: if WRITE_SIZE > 49152 KB the accs spilled -> revert.
// ===========================================================================
union SmemQKV {
  unsigned short st[4][2][4096];   // [A,Bq,Bk,Bv][panel p][8 KB] = 64 KB
  unsigned short epi[128 * 136];   // epilogue staging (34816 B)
};

__global__ __launch_bounds__(256, 2)
void gemm_qkv(const unsigned short* __restrict__ A,
              const unsigned short* __restrict__ Wt,   // [3][N][K] k-contig
              const float* __restrict__ b0, const float* __restrict__ b1,
              const float* __restrict__ b2,
              unsigned short* __restrict__ O0, unsigned short* __restrict__ O1,
              unsigned short* __restrict__ O2,
              int M, int N, int K)
{
  __shared__ SmemQKV smem;

  const int tid = threadIdx.x;
  const int wave = tid >> 6, lane = tid & 63;
  const int wm = wave >> 1, wn = wave & 1;
  const int quad = lane >> 4, l16 = lane & 15;

  // ---- XCD-aware 4x4-square swizzle (T = 8*64 = 512, %128==0; z==0) ----
  const int gx = gridDim.x, gy = gridDim.y;
  int bm, bn;
  {
    int f = blockIdx.y * gx + blockIdx.x;
    int T = gx * gy;
    int nsq = T >> 7;
    int xcd = f & 7, i = f >> 3;
    int sq = xcd * nsq + (i >> 4);
    int w = i & 15;
    int sqm = sq / (gx >> 2), sqn = sq - sqm * (gx >> 2);
    bm = (sqm * 4 + (w >> 2)) * 128;
    bn = (sqn * 4 + (w & 3)) * 128;
  }

  const unsigned short* Bq = Wt;
  const unsigned short* Bk = Wt + (long)N * K;
  const unsigned short* Bv = Wt + 2L * N * K;

  floatx4 acc[3][4][4];
  #pragma unroll
  for (int s = 0; s < 3; s++)
    #pragma unroll
    for (int i = 0; i < 4; i++)
      #pragma unroll
      for (int j = 0; j < 4; j++)
        acc[s][i][j] = (floatx4){0.f, 0.f, 0.f, 0.f};

  char* asb = (char*)&smem.st[0][0][0] + wave * 1024;
  char* qb  = (char*)&smem.st[1][0][0] + wave * 1024;
  char* kb  = (char*)&smem.st[2][0][0] + wave * 1024;
  char* vb  = (char*)&smem.st[3][0][0] + wave * 1024;

  for (int k0 = 0; k0 < K; k0 += 64) {
    #pragma unroll
    for (int p = 0; p < 2; p++) {
      #pragma unroll
      for (int h = 0; h < 2; h++) {
        int flat = tid + h * 256;          // 16B-chunk index within panel
        int r = flat >> 2, c = (flat & 3) << 3;
        long offA = (long)(bm + r) * K + k0 + p * 32 + c;
        long offB = (long)(bn + r) * K + k0 + p * 32 + c;
        int dst = p * 8192 + h * 4096;
        async16(A  + offA, asb + dst);
        async16(Bq + offB, qb  + dst);
        async16(Bk + offB, kb  + dst);
        async16(Bv + offB, vb  + dst);
      }
    }
    __syncthreads();

    #pragma unroll
    for (int ks = 0; ks < 2; ks++) {
      short8 afr[4];
      #pragma unroll
      for (int i = 0; i < 4; i++)
        afr[i] = *(const short8*)&smem.st[0][ks][(wm * 64 + i * 16 + l16) * 32 + quad * 8];
      #pragma unroll
      for (int s = 0; s < 3; s++) {
        short8 bfr[4];
        #pragma unroll
        for (int i = 0; i < 4; i++)
          bfr[i] = *(const short8*)&smem.st[1 + s][ks][(wn * 64 + i * 16 + l16) * 32 + quad * 8];
        #pragma unroll
        for (int mi = 0; mi < 4; mi++)
          #pragma unroll
          for (int ni = 0; ni < 4; ni++)
            acc[s][mi][ni] = __builtin_amdgcn_mfma_f32_16x16x32_bf16(
                afr[mi], bfr[ni], acc[s][mi][ni], 0, 0, 0);
      }
    }
    __syncthreads();
  }

  // ---- epilogue: 3 sequential passes through the epi buffer ----
  #pragma unroll
  for (int zz = 0; zz < 3; zz++) {
    const float* bias = (zz == 0) ? b0 : ((zz == 1) ? b1 : b2);
    float bi[4];
    #pragma unroll
    for (int ni = 0; ni < 4; ni++) bi[ni] = bias[bn + wn * 64 + ni * 16 + l16];

    #pragma unroll
    for (int ni = 0; ni < 4; ni++) {
      int col = wn * 64 + ni * 16 + l16;
      #pragma unroll
      for (int mi = 0; mi < 4; mi++) {
        int row0 = wm * 64 + mi * 16 + quad * 4;
        if (zz < 2) {
          #pragma unroll
          for (int r = 0; r < 4; r++)
            smem.epi[(row0 + r) * 136 + col] = f2bf(acc[zz][mi][ni][r] + bi[ni]);
        } else {
          #pragma unroll
          for (int r = 0; r < 4; r += 2) {
            unsigned lo = f2bf(acc[2][mi][ni][r] + bi[ni]);
            unsigned hi = f2bf(acc[2][mi][ni][r + 1] + bi[ni]);
            *(unsigned*)&smem.epi[col * 136 + row0 + r] = lo | (hi << 16);
          }
        }
      }
    }
    __syncthreads();

    #pragma unroll
    for (int i = 0; i < 8; i++) {
      int flat = i * 2048 + tid * 8;
      int rr = flat >> 7, cc = flat & 127;
      short8 vline = *(const short8*)&smem.epi[rr * 136 + cc];
      if (zz == 0) {
        *(short8*)&O0[(long)(bm + rr) * N + bn + cc] = vline;
      } else if (zz == 1) {
        *(short8*)&O1[(long)(bm + rr) * N + bn + cc] = vline;
      } else {
        int bb = bm >> 11, s0 = bm & 2047;  // S=2048, tiles don't straddle batch
        *(short8*)&O2[(long)bb * (1024L * 2048) + (long)(bn + rr) * 2048 + s0 + cc] = vline;
      }
    }
    if (zz < 2) __syncthreads();   // epi reused next pass
  }
}

// ===========================================================================
// gemm256: 256x256 8-phase kernel (R4 version). Used ONLY for MODE_S
// (256 blocks = exact 1.0 fill at 1 block/CU; measured -3.5 us vs legacy).
// ===========================================================================

__device__ __forceinline__ void stage_half(const unsigned short* gp, long rowbase,
                                           int ldk, int kb, char* region,
                                           int wave, int lane) {
  const int rs = lane >> 3;
  const int kc = ((lane & 7) ^ rs) << 3;
  #pragma unroll
  for (int h = 0; h < 2; h++) {
    const int rr = (h * 8 + wave) * 8 + rs;
    async16(gp + (rowbase + rr) * (long)ldk + kb + kc,
            region + (h * 8 + wave) * 1024);
  }
}

__device__ __forceinline__ short8 frag(const char* region, int hr, int ks, int quad) {
  return *(const short8*)(region + hr * 128 + ((((ks << 2) | quad) ^ (hr & 7)) << 4));
}

#define MFMA_QUAD(MH, NH)                                                    \
  do {                                                                       \
    _Pragma("unroll")                                                        \
    for (int mi_ = 0; mi_ < 4; mi_++) {                                      \
      _Pragma("unroll")                                                      \
      for (int jj_ = 0; jj_ < 2; jj_++) {                                    \
        _Pragma("unroll")                                                    \
        for (int ks_ = 0; ks_ < 2; ks_++) {                                  \
          acc[MH][mi_][NH][jj_] = __builtin_amdgcn_mfma_f32_16x16x32_bf16(   \
              a[mi_][ks_], b[NH][jj_][ks_], acc[MH][mi_][NH][jj_], 0, 0, 0); \
        }                                                                    \
      }                                                                      \
    }                                                                        \
  } while (0)

template<int MODE>
__global__ __launch_bounds__(512, 1)
void gemm256(const unsigned short* __restrict__ A,
             const unsigned short* __restrict__ Bmat,
             const float* __restrict__ b0, const float* __restrict__ b1,
             const float* __restrict__ b2,
             unsigned short* __restrict__ O0, unsigned short* __restrict__ O1,
             unsigned short* __restrict__ O2, float* __restrict__ Of,
             float* __restrict__ lsum,
             int M, int N, int K, long aZ, long bZ, long cZ, float scale)
{
  __shared__ __attribute__((aligned(128))) char lds[131072];

  const int tid = threadIdx.x;
  const int wave = tid >> 6, lane = tid & 63;
  const int wm = wave >> 2, wn = wave & 3;
  const int quad = lane >> 4, l16 = lane & 15;

  const int gx = gridDim.x, gy = gridDim.y;
  int z, bm, bn;
  {
    int f = (blockIdx.z * gy + blockIdx.y) * gx + blockIdx.x;
    int T = gx * gy * (int)gridDim.z;
    int nsq = T >> 7;
    int xcd = f & 7, i = f >> 3;
    int sq = xcd * nsq + (i >> 4);
    int w = i & 15;
    int spz = (gx >> 2) * (gy >> 2);
    z = sq / spz;
    int sqr = sq - z * spz;
    int sqm = sqr / (gx >> 2), sqn = sqr - sqm * (gx >> 2);
    bm = (sqm * 4 + (w >> 2)) * 256;
    bn = (sqn * 4 + (w & 3)) * 256;
  }

  const unsigned short* Ap = (MODE == MODE_QKV) ? A : (A + (long)z * aZ);
  const unsigned short* Bp = Bmat + (long)z * bZ;

  const int NT = K >> 6;

  stage_half(Ap, bm,       K, 0,  lds +     0, wave, lane);
  stage_half(Bp, bn,       K, 0,  lds + 32768, wave, lane);
  stage_half(Bp, bn + 128, K, 0,  lds + 49152, wave, lane);
  stage_half(Ap, bm + 128, K, 0,  lds + 16384, wave, lane);
  stage_half(Ap, bm,       K, 64, lds + 65536 +     0, wave, lane);
  stage_half(Bp, bn,       K, 64, lds + 65536 + 32768, wave, lane);
  stage_half(Bp, bn + 128, K, 64, lds + 65536 + 49152, wave, lane);
  asm volatile("s_waitcnt vmcnt(6)" ::: "memory");
  bar_raw();

  floatx4 acc[2][4][2][2];
  #pragma unroll
  for (int p = 0; p < 2; p++)
    #pragma unroll
    for (int q2 = 0; q2 < 4; q2++)
      #pragma unroll
      for (int r = 0; r < 2; r++)
        #pragma unroll
        for (int s = 0; s < 2; s++)
          acc[p][q2][r][s] = (floatx4){0.f, 0.f, 0.f, 0.f};

  short8 a[4][2];
  short8 b[2][2][2];

  for (int j = 0; j < NT; j++) {
    char* bufc = lds + ((j & 1) << 16);
    char* bufn = lds + (((j + 1) & 1) << 16);
    const bool lp = (j + 2 >= NT);
    const int kn  = (j + 1) << 6;
    const int kn2 = (j + 2) << 6;

    // ---- phase 0 ----
    #pragma unroll
    for (int mi = 0; mi < 4; mi++)
      #pragma unroll
      for (int ks = 0; ks < 2; ks++)
        a[mi][ks] = frag(bufc, wm * 64 + mi * 16 + l16, ks, quad);
    #pragma unroll
    for (int jj = 0; jj < 2; jj++)
      #pragma unroll
      for (int ks = 0; ks < 2; ks++)
        b[0][jj][ks] = frag(bufc + 32768, wn * 32 + jj * 16 + l16, ks, quad);
    if (j + 1 < NT)
      stage_half(Ap, bm + 128, K, kn, bufn + 16384, wave, lane);
    bar_raw();
    asm volatile("s_waitcnt lgkmcnt(0)" ::: "memory");
    __builtin_amdgcn_s_setprio(1);
    MFMA_QUAD(0, 0);
    __builtin_amdgcn_s_setprio(0);
    bar_raw();

    // ---- phase 1 ----
    #pragma unroll
    for (int jj = 0; jj < 2; jj++)
      #pragma unroll
      for (int ks = 0; ks < 2; ks++)
        b[1][jj][ks] = frag(bufc + 49152, wn * 32 + jj * 16 + l16, ks, quad);
    if (!lp)
      stage_half(Ap, bm, K, kn2, bufc, wave, lane);
    bar_raw();
    asm volatile("s_waitcnt lgkmcnt(0)" ::: "memory");
    __builtin_amdgcn_s_setprio(1);
    MFMA_QUAD(0, 1);
    __builtin_amdgcn_s_setprio(0);
    bar_raw();

    // ---- phase 2 ----
    #pragma unroll
    for (int mi = 0; mi < 4; mi++)
      #pragma unroll
      for (int ks = 0; ks < 2; ks++)
        a[mi][ks] = frag(bufc + 16384, wm * 64 + mi * 16 + l16, ks, quad);
    if (!lp)
      stage_half(Bp, bn, K, kn2, bufc + 32768, wave, lane);
    bar_raw();
    asm volatile("s_waitcnt lgkmcnt(0)" ::: "memory");
    __builtin_amdgcn_s_setprio(1);
    MFMA_QUAD(1, 0);
    __builtin_amdgcn_s_setprio(0);
    bar_raw();

    // ---- phase 3 ----
    if (!lp) {
      stage_half(Bp, bn + 128, K, kn2, bufc + 49152, wave, lane);
      asm volatile("s_waitcnt vmcnt(6)" ::: "memory");
    } else {
      asm volatile("s_waitcnt vmcnt(0)" ::: "memory");
    }
    bar_raw();
    __builtin_amdgcn_s_setprio(1);
    MFMA_QUAD(1, 1);
    __builtin_amdgcn_s_setprio(0);
    bar_raw();
  }

  if (MODE == MODE_PV) {
    #pragma unroll
    for (int mh = 0; mh < 2; mh++)
      #pragma unroll
      for (int mi = 0; mi < 4; mi++) {
        const int row0 = bm + mh * 128 + wm * 64 + mi * 16 + quad * 4;
        float inv[4];
        #pragma unroll
        for (int r = 0; r < 4; r++)
          inv[r] = 1.0f / lsum[(long)z * M + row0 + r];
        #pragma unroll
        for (int nh = 0; nh < 2; nh++)
          #pragma unroll
          for (int jj = 0; jj < 2; jj++) {
            const int col = bn + nh * 128 + wn * 32 + jj * 16 + l16;
            #pragma unroll
            for (int r = 0; r < 4; r++)
              Of[(long)z * cZ + (long)(row0 + r) * N + col] =
                  acc[mh][mi][nh][jj][r] * inv[r];
          }
      }
    return;
  }

  const bool vtrans = (MODE == MODE_QKV) && (z == 2);
  float bi[2][2];
  if (MODE == MODE_QKV) {
    const float* bias = (z == 0) ? b0 : ((z == 1) ? b1 : b2);
    #pragma unroll
    for (int nh = 0; nh < 2; nh++)
      #pragma unroll
      for (int jj = 0; jj < 2; jj++)
        bi[nh][jj] = bias[bn + nh * 128 + wn * 32 + jj * 16 + l16];
  }

  unsigned short* epi = (unsigned short*)lds;
  #pragma unroll
  for (int mh = 0; mh < 2; mh++) {
    #pragma unroll
    for (int mi = 0; mi < 4; mi++) {
      const int r0 = wm * 64 + mi * 16 + quad * 4;
      #pragma unroll
      for (int nh = 0; nh < 2; nh++)
        #pragma unroll
        for (int jj = 0; jj < 2; jj++) {
          const int col = nh * 128 + wn * 32 + jj * 16 + l16;
          if (MODE == MODE_S) {
            #pragma unroll
            for (int r = 0; r < 4; r++)
              epi[(r0 + r) * 264 + col] = f2bf(__expf(acc[mh][mi][nh][jj][r] * scale));
          } else if (!vtrans) {
            #pragma unroll
            for (int r = 0; r < 4; r++)
              epi[(r0 + r) * 264 + col] = f2bf(acc[mh][mi][nh][jj][r] + bi[nh][jj]);
          } else {
            #pragma unroll
            for (int r = 0; r < 4; r += 2) {
              unsigned lo = f2bf(acc[mh][mi][nh][jj][r] + bi[nh][jj]);
              unsigned hi = f2bf(acc[mh][mi][nh][jj][r + 1] + bi[nh][jj]);
              *(unsigned*)&epi[col * 136 + r0 + r] = lo | (hi << 16);
            }
          }
        }
    }
    __syncthreads();

    if (!vtrans) {
      #pragma unroll
      for (int it = 0; it < 8; it++) {
        int flat = it * 4096 + tid * 8;
        int rr = flat >> 8, cc = flat & 255;
        short8 vline = *(const short8*)&epi[rr * 264 + cc];
        long grow = bm + mh * 128 + rr;
        if (MODE == MODE_S) {
          union { short8 v; unsigned short u[8]; } t; t.v = vline;
          float s8 = 0.f;
          #pragma unroll
          for (int jq = 0; jq < 8; jq++) s8 += bf2f(t.u[jq]);
          s8 += __shfl_xor(s8, 1);
          s8 += __shfl_xor(s8, 2);
          s8 += __shfl_xor(s8, 4);
          s8 += __shfl_xor(s8, 8);
          s8 += __shfl_xor(s8, 16);
          if ((lane & 31) == 0) atomicAdd(&lsum[(long)z * M + grow], s8);
          *(short8*)&O0[(long)z * cZ + grow * N + bn + cc] = vline;
        } else {
          unsigned short* O = (z == 0) ? O0 : O1;
          *(short8*)&O[grow * N + bn + cc] = vline;
        }
      }
    } else {
      int bb2 = bm >> 11, s0 = bm & 2047;
      #pragma unroll
      for (int it = 0; it < 8; it++) {
        int flat = it * 4096 + tid * 8;
        int dd = flat >> 7, ss = flat & 127;
        short8 vline = *(const short8*)&epi[dd * 136 + ss];
        *(short8*)&O2[(long)bb2 * (1024L * 2048) + (long)(bn + dd) * 2048 + s0 + mh * 128 + ss] = vline;
      }
    }
    if (mh == 0) __syncthreads();
  }
}

// ===========================================================================
// Legacy 128x128 kernel: best measured for PV; fallback S/PV.
// ===========================================================================

union SmemU {
  struct { unsigned short A[2][4096]; unsigned short B[2][4096]; } st;  // 32 KB
  unsigned short epi[128 * 136];                                        // 34816 B
};

template<int MODE>
__global__ __launch_bounds__(256, 4)
void gemm_nt(const unsigned short* __restrict__ A,
             const unsigned short* __restrict__ Bmat,
             const float* __restrict__ b0, const float* __restrict__ b1,
             const float* __restrict__ b2,
             unsigned short* __restrict__ O0, unsigned short* __restrict__ O1,
             unsigned short* __restrict__ O2,
             float* __restrict__ Of, float* __restrict__ lsum,
             int M, int N, int K, long aZ, long bZ, long cZ, float scale)
{
  __shared__ SmemU smem;

  const int tid = threadIdx.x;
  const int wave = tid >> 6, lane = tid & 63;
  const int wm = wave >> 1, wn = wave & 1;
  const int quad = lane >> 4, l16 = lane & 15;

  const int gx = gridDim.x, gy = gridDim.y;
  int z, bm, bn;
  {
    int f = (blockIdx.z * gy + blockIdx.y) * gx + blockIdx.x;
    int T = gx * gy * (int)gridDim.z;
    int nsq = T >> 7;
    int xcd = f & 7, i = f >> 3;
    int sq = xcd * nsq + (i >> 4);
    int w = i & 15;
    int spz = (gx >> 2) * (gy >> 2);
    z = sq / spz;
    int sqr = sq - z * spz;
    int sqm = sqr / (gx >> 2), sqn = sqr - sqm * (gx >> 2);
    bm = (sqm * 4 + (w >> 2)) * 128;
    bn = (sqn * 4 + (w & 3)) * 128;
  }

  const unsigned short* Ap = (MODE == MODE_QKV) ? A : (A + (long)z * aZ);
  const unsigned short* Bp = Bmat + (long)z * bZ;

  floatx4 acc[4][4];
  #pragma unroll
  for (int i = 0; i < 4; i++)
    #pragma unroll
    for (int j = 0; j < 4; j++)
      acc[i][j] = (floatx4){0.f, 0.f, 0.f, 0.f};

  char* asb = (char*)&smem.st.A[0][0] + wave * 1024;
  char* bsb = (char*)&smem.st.B[0][0] + wave * 1024;

  for (int k0 = 0; k0 < K; k0 += 64) {
    #pragma unroll
    for (int p = 0; p < 2; p++) {
      #pragma unroll
      for (int h = 0; h < 2; h++) {
        int flat = tid + h * 256;
        int r = flat >> 2, c = (flat & 3) << 3;
        async16(Ap + (long)(bm + r) * K + k0 + p * 32 + c,
                asb + p * 8192 + h * 4096);
        async16(Bp + (long)(bn + r) * K + k0 + p * 32 + c,
                bsb + p * 8192 + h * 4096);
      }
    }
    __syncthreads();

    #pragma unroll
    for (int ks = 0; ks < 2; ks++) {
      short8 afr[4], bfr[4];
      #pragma unroll
      for (int i = 0; i < 4; i++)
        afr[i] = *(const short8*)&smem.st.A[ks][(wm * 64 + i * 16 + l16) * 32 + quad * 8];
      #pragma unroll
      for (int i = 0; i < 4; i++)
        bfr[i] = *(const short8*)&smem.st.B[ks][(wn * 64 + i * 16 + l16) * 32 + quad * 8];
      #pragma unroll
      for (int mi = 0; mi < 4; mi++)
        #pragma unroll
        for (int ni = 0; ni < 4; ni++)
          acc[mi][ni] = __builtin_amdgcn_mfma_f32_16x16x32_bf16(
              afr[mi], bfr[ni], acc[mi][ni], 0, 0, 0);
    }
    __syncthreads();
  }

  if (MODE == MODE_PV) {
    #pragma unroll
    for (int mi = 0; mi < 4; mi++) {
      int row0 = bm + wm * 64 + mi * 16 + quad * 4;
      float inv[4];
      #pragma unroll
      for (int r = 0; r < 4; r++)
        inv[r] = 1.0f / lsum[(long)z * M + row0 + r];
      #pragma unroll
      for (int ni = 0; ni < 4; ni++) {
        int col = bn + wn * 64 + ni * 16 + l16;
        #pragma unroll
        for (int r = 0; r < 4; r++)
          Of[(long)z * cZ + (long)(row0 + r) * N + col] = acc[mi][ni][r] * inv[r];
      }
    }
    return;
  }

  const bool vtrans = (MODE == MODE_QKV) && (z == 2);
  float bi[4];
  if (MODE == MODE_QKV) {
    const float* bias = (z == 0) ? b0 : ((z == 1) ? b1 : b2);
    #pragma unroll
    for (int ni = 0; ni < 4; ni++) bi[ni] = bias[bn + wn * 64 + ni * 16 + l16];
  }

  #pragma unroll
  for (int ni = 0; ni < 4; ni++) {
    int col = wn * 64 + ni * 16 + l16;
    float bb = (MODE == MODE_QKV) ? bi[ni] : 0.f;
    #pragma unroll
    for (int mi = 0; mi < 4; mi++) {
      int row0 = wm * 64 + mi * 16 + quad * 4;
      if (MODE == MODE_S) {
        #pragma unroll
        for (int r = 0; r < 4; r++)
          smem.epi[(row0 + r) * 136 + col] = f2bf(__expf(acc[mi][ni][r] * scale));
      } else if (!vtrans) {
        #pragma unroll
        for (int r = 0; r < 4; r++)
          smem.epi[(row0 + r) * 136 + col] = f2bf(acc[mi][ni][r] + bb);
      } else {
        #pragma unroll
        for (int r = 0; r < 4; r += 2) {
          unsigned lo = f2bf(acc[mi][ni][r] + bb);
          unsigned hi = f2bf(acc[mi][ni][r + 1] + bb);
          *(unsigned*)&smem.epi[col * 136 + row0 + r] = lo | (hi << 16);
        }
      }
    }
  }
  __syncthreads();

  #pragma unroll
  for (int i = 0; i < 8; i++) {
    int flat = i * 2048 + tid * 8;
    int rr = flat >> 7, cc = flat & 127;
    short8 vline = *(const short8*)&smem.epi[rr * 136 + cc];
    if (MODE == MODE_S) {
      union { short8 v; unsigned short u[8]; } t; t.v = vline;
      float s8 = 0.f;
      #pragma unroll
      for (int j = 0; j < 8; j++) s8 += bf2f(t.u[j]);
      s8 += __shfl_xor(s8, 1);
      s8 += __shfl_xor(s8, 2);
      s8 += __shfl_xor(s8, 4);
      s8 += __shfl_xor(s8, 8);
      if ((lane & 15) == 0) atomicAdd(&lsum[(long)z * M + bm + rr], s8);
      *(short8*)&O0[(long)z * cZ + (long)(bm + rr) * N + bn + cc] = vline;
    } else if (!vtrans) {
      unsigned short* O = (z == 0) ? O0 : O1;
      *(short8*)&O[(long)(bm + rr) * N + bn + cc] = vline;
    } else {
      int bb = bm >> 11, s0 = bm & 2047;
      *(short8*)&O2[(long)bb * (1024L * 2048) + (long)(bn + rr) * 2048 + s0 + cc] = vline;
    }
  }
}

// Fused prep: [0,4096) x fp32->bf16; [4096,7168) W transpose->bf16;
// [7168,7200) zero the 8192-float lsum buffer.
__global__ __launch_bounds__(256)
void prep_kernel(const float* __restrict__ x, unsigned short* __restrict__ xb,
                 const float* __restrict__ W0, const float* __restrict__ W1,
                 const float* __restrict__ W2, unsigned short* __restrict__ Wt,
                 float* __restrict__ lsum) {
  int blk = blockIdx.x;
  if (blk < 4096) {
    long i = ((long)blk * 256 + threadIdx.x) * 8;
    float4 a = *(const float4*)(x + i);
    float4 b = *(const float4*)(x + i + 4);
    union { int4 v; unsigned short u[8]; } t;
    t.u[0] = f2bf(a.x); t.u[1] = f2bf(a.y); t.u[2] = f2bf(a.z); t.u[3] = f2bf(a.w);
    t.u[4] = f2bf(b.x); t.u[5] = f2bf(b.y); t.u[6] = f2bf(b.z); t.u[7] = f2bf(b.w);
    *(int4*)(xb + i) = t.v;
  } else if (blk < 7168) {
    __shared__ float tile[32][33];
    int tt = blk - 4096;
    int zz = tt >> 10, rem = tt & 1023;
    int kb = (rem >> 5) * 32, nb = (rem & 31) * 32;
    const float* W = (zz == 0) ? W0 : ((zz == 1) ? W1 : W2);
    unsigned short* O = Wt + (long)zz * 1024 * 1024;
    int t = threadIdx.x, tr = t >> 5, tc = t & 31;
    #pragma unroll
    for (int i = 0; i < 4; i++)
      tile[tr + i * 8][tc] = W[(long)(kb + tr + i * 8) * 1024 + nb + tc];
    __syncthreads();
    #pragma unroll
    for (int i = 0; i < 4; i++)
      O[(long)(nb + tr + i * 8) * 1024 + kb + tc] = f2bf(tile[tc][tr + i * 8]);
  } else {
    int i = (blk - 7168) * 256 + threadIdx.x;  // 32*256 = 8192 floats
    lsum[i] = 0.f;
  }
}

extern "C" void kernel_launch(void* const* d_in, const int* in_sizes, int n_in,
                              void* d_out, int out_size, void* d_ws, size_t ws_size,
                              hipStream_t stream) {
  const float* x  = (const float*)d_in[0];
  const float* Wq = (const float*)d_in[1];
  const float* bq = (const float*)d_in[2];
  const float* Wk = (const float*)d_in[3];
  const float* bk = (const float*)d_in[4];
  const float* Wv = (const float*)d_in[5];
  const float* bv = (const float*)d_in[6];
  float* out = (float*)d_out;

  const int B = 4, S = 2048, D = 1024;
  const int M = B * S;
  const float scale = 0.03125f;  // 1/sqrt(1024)

  // xb (16 MiB) + Wt (6 MiB) borrow d_out's first 22 MiB; dead before the
  // PV GEMM overwrites all of d_out.
  unsigned short* xb = (unsigned short*)d_out;
  unsigned short* Wt = xb + (size_t)M * D;
  unsigned short* q  = (unsigned short*)d_ws;
  unsigned short* k  = q + (size_t)M * D;
  unsigned short* vT = k + (size_t)M * D;
  unsigned short* P  = vT + (size_t)M * D;

  size_t need_full = ((size_t)3 * M * D + (size_t)B * S * S) * sizeof(unsigned short)
                   + (size_t)M * sizeof(float);
  const bool full = (ws_size >= need_full);
  float* lsum = full ? (float*)(P + (size_t)B * S * S)
                     : (float*)(P + (size_t)S * S);

  prep_kernel<<<7200, 256, 0, stream>>>(x, xb, Wq, Wk, Wv, Wt, lsum);

  // QKV: FUSED kernel -- one A-stage feeds 3 accumulator sets; 512 blocks
  // at 2 blocks/CU = exact 1.0 fill.
  gemm_qkv<<<dim3(D / 128, M / 128), 256, 0, stream>>>(
      xb, Wt, bq, bk, bv, q, k, vT, M, D, D);

  if (full) {
    // S: 256^2 8-phase (256 blocks = exact 1.0 fill; measured -3.5 us)
    gemm256<MODE_S><<<dim3(S / 256, S / 256, B), 512, 0, stream>>>(
        q, k, nullptr, nullptr, nullptr, P, nullptr, nullptr, nullptr, lsum,
        S, S, D, (long)S * D, (long)S * D, (long)S * S, scale);
    // PV: legacy
    gemm_nt<MODE_PV><<<dim3(D / 128, S / 128, B), 256, 0, stream>>>(
        P, vT, nullptr, nullptr, nullptr, nullptr, nullptr, nullptr, out, lsum,
        S, D, S, (long)S * S, (long)D * S, (long)S * D, 1.0f);
  } else {
    for (int b = 0; b < B; b++) {
      const unsigned short* qb = q + (size_t)b * S * D;
      const unsigned short* kb = k + (size_t)b * S * D;
      const unsigned short* vb = vT + (size_t)b * S * D;
      float* ob = out + (size_t)b * S * D;
      gemm_nt<MODE_S><<<dim3(S / 128, S / 128, 1), 256, 0, stream>>>(
          qb, kb, nullptr, nullptr, nullptr, P, nullptr, nullptr, nullptr,
          lsum + (size_t)b * S,
          S, S, D, 0, 0, 0, scale);
      gemm_nt<MODE_PV><<<dim3(D / 128, S / 128, 1), 256, 0, stream>>>(
          P, vb, nullptr, nullptr, nullptr, nullptr, nullptr, nullptr, ob,
          lsum + (size_t)b * S,
          S, D, S, 0, 0, 0, 1.0f);
    }
  }
}